// Round 5
// baseline (447.760 us; speedup 1.0000x reference)
//
#include <hip/hip_runtime.h>
#include <cstdint>

typedef unsigned short u16;
typedef __bf16 bf16x8 __attribute__((ext_vector_type(8)));
typedef float f32x4 __attribute__((ext_vector_type(4)));
typedef u16 u16x8 __attribute__((ext_vector_type(8)));

#define B_DIM 32
#define S_DIM 2048
#define D_DIM 1024
#define U_DIM 1024
#define M_TOT (B_DIM * S_DIM)   // 65536 rows

// ---------- helpers ----------
__device__ __forceinline__ u16 f2bf(float f) {
    union { float f; uint32_t u; } a; a.f = f;
    uint32_t u = a.u;
    uint32_t r = (u + 0x7FFFu + ((u >> 16) & 1u)) >> 16;   // RNE
    return (u16)r;
}
__device__ __forceinline__ float bf2f(u16 h) {
    union { uint32_t u; float f; } a; a.u = ((uint32_t)h) << 16;
    return a.f;
}
__device__ __forceinline__ float fast_tanh(float x) {
    float ax = fabsf(x);
    float e  = __expf(-2.0f * ax);
    float th = __fdividef(1.0f - e, 1.0f + e);
    return copysignf(th, x);
}
// global -> LDS async copy, 16B per lane
__device__ __forceinline__ void gload_lds16(const void* g, void* l) {
    __builtin_amdgcn_global_load_lds(
        (__attribute__((address_space(1))) void*)(uintptr_t)g,
        (__attribute__((address_space(3))) void*)(uint32_t)(uintptr_t)l,
        16, 0, 0);
}

// ---------- kernel 1a: values f32 -> bf16 ----------
__global__ void convert_values_kernel(const float4* __restrict__ in, ushort4* __restrict__ out, long n4) {
    long i = (long)blockIdx.x * blockDim.x + threadIdx.x;
    long stride = (long)gridDim.x * blockDim.x;
    for (; i < n4; i += stride) {
        float4 v = in[i];
        ushort4 o;
        o.x = f2bf(v.x); o.y = f2bf(v.y); o.z = f2bf(v.z); o.w = f2bf(v.w);
        out[i] = o;
    }
}

// ---------- kernel 1b: w2 [D][U] f32 -> w2t [U][D] bf16 ----------
__global__ void transpose_w2_kernel(const float* __restrict__ w2, u16* __restrict__ w2t) {
    __shared__ float tile[32][33];
    int bx = blockIdx.x * 32, by = blockIdx.y * 32;
    int tx = threadIdx.x, ty = threadIdx.y;  // (32, 8)
    for (int i = 0; i < 32; i += 8)
        tile[ty + i][tx] = w2[(size_t)(by + ty + i) * U_DIM + bx + tx];
    __syncthreads();
    for (int i = 0; i < 32; i += 8)
        w2t[(size_t)(bx + ty + i) * D_DIM + by + tx] = f2bf(tile[tx][ty + i]);
}

// ---------- kernel 1c: qpb = query@w1 + b1 + b2, w1 read exactly once ----------
// grid 32, block 256: block handles u-cols [bx*32, bx*32+32) for all 32 batches
__global__ void qproj_kernel(const float* __restrict__ q, const float* __restrict__ w1,
                             const float* __restrict__ b1, const float* __restrict__ b2,
                             float* __restrict__ qpb) {
    const int u0 = blockIdx.x * 32;
    const int ul = threadIdx.x & 31;   // u within slab
    const int bg = threadIdx.x >> 5;   // 0..7 -> handles b = bg*4 .. bg*4+3
    __shared__ float qc[32][128];      // [b][d-chunk]
    __shared__ float wc[128][32];      // [d][u]
    float acc[4] = {0.f, 0.f, 0.f, 0.f};
    for (int dc = 0; dc < D_DIM; dc += 128) {
        __syncthreads();
        for (int i = threadIdx.x; i < 4096; i += 256)
            qc[i >> 7][i & 127] = q[(size_t)(i >> 7) * D_DIM + dc + (i & 127)];
        for (int i = threadIdx.x; i < 4096; i += 256)
            wc[i >> 5][i & 31] = w1[(size_t)(dc + (i >> 5)) * U_DIM + u0 + (i & 31)];
        __syncthreads();
        for (int d = 0; d < 128; ++d) {
            float w = wc[d][ul];
#pragma unroll
            for (int i = 0; i < 4; ++i) acc[i] += qc[bg * 4 + i][d] * w;
        }
    }
    const float bias = b1[u0 + ul] + b2[u0 + ul];
#pragma unroll
    for (int i = 0; i < 4; ++i) qpb[(bg * 4 + i) * U_DIM + u0 + ul] = acc[i] + bias;
}

// ---------- kernel 2: 256x256-tile, 8-wave, 4-phase/K-tile, counted-vmcnt GEMM ----------
// k-octet-major LDS: elem addr = colblk*2048 + row*8, colblk = k/8 (0..7).
// Conflict-free by construction; all fragment reads use immediate offsets.
__global__ __launch_bounds__(512, 2)
void score_gemm8_kernel(const u16* __restrict__ vbf, const u16* __restrict__ w2t,
                        const float* __restrict__ qpb, const float* __restrict__ vvec,
                        float* __restrict__ spart) {
    const int p    = blockIdx.x;
    const int xcd  = p & 7;
    const int slot = p >> 3;
    const int mt   = xcd * 32 + (slot >> 2);   // 0..255
    const int nt   = slot & 3;                 // 0..3
    const int m0 = mt * 256;
    const int n0 = nt * 256;
    const int b  = m0 >> 11;

    __shared__ __align__(16) __bf16 Abuf[2][256 * 64];   // 64 KB
    __shared__ __align__(16) __bf16 Bbuf[2][256 * 64];   // 64 KB
    __shared__ float qv_lds[256], vv_lds[256];
    __shared__ float red[4][256];

    const int tid  = threadIdx.x;
    const int lane = tid & 63;
    const int wid  = tid >> 6;     // 0..7
    const int wm   = wid >> 2;     // 0..1  (M split)
    const int wn   = wid & 3;      // 0..3  (N split)

    if (tid < 256) qv_lds[tid] = qpb[b * U_DIM + n0 + tid];
    else           vv_lds[tid - 256] = vvec[n0 + (tid - 256)];

    // staging: issue j writes LDS elems [j*4096 + tid*8, +8) = (colblk=j*2+(tid>>8), row=tid&255)
    // global source: row (tid&255), k-octet (j*2 + tid>>8) within the K-tile
    const int srow = tid & 255;
    const int socb = tid >> 8;     // 0 or 1
    const u16* asrcb = vbf + (size_t)(m0 + srow) * D_DIM + socb * 8;
    const u16* bsrcb = w2t + (size_t)(n0 + srow) * D_DIM + socb * 8;

    // prologue: stage K-tile 0 into buffer 0
#pragma unroll
    for (int j = 0; j < 4; ++j) {
        gload_lds16(asrcb + j * 16, &Abuf[0][j * 4096 + tid * 8]);
        gload_lds16(bsrcb + j * 16, &Bbuf[0][j * 4096 + tid * 8]);
    }

    f32x4 acc[8][4];
#pragma unroll
    for (int mi = 0; mi < 8; ++mi)
#pragma unroll
        for (int nj = 0; nj < 4; ++nj) acc[mi][nj] = (f32x4){0.f, 0.f, 0.f, 0.f};

    const int colL = lane & 15;
    const int grp  = lane >> 4;
    // fragment read bases (elems); all further offsets are compile-time immediates
    const int base_a = grp * 2048 + (wm * 128 + colL) * 8;
    const int base_b = grp * 2048 + (wn * 64 + colL) * 8;

    bf16x8 aR[4], bR0[4], bR1[4];

    for (int t = 0; t < 16; ++t) {
        const int cur = t & 1, nxt = cur ^ 1;
        const __bf16* Ac = Abuf[cur];
        const __bf16* Bc = Bbuf[cur];
        const size_t kofs = (size_t)(t + 1) * 64;

        // ================= P0: stage A j0,j1 of t+1; wait tile t; MFMA (kk0, mi0-3) ====
        if (t < 15) {
            gload_lds16(asrcb + kofs,      &Abuf[nxt][tid * 8]);
            gload_lds16(asrcb + kofs + 16, &Abuf[nxt][4096 + tid * 8]);
            asm volatile("s_waitcnt vmcnt(2)" ::: "memory");   // all 8 of tile t landed
        } else {
            asm volatile("s_waitcnt vmcnt(0)" ::: "memory");
        }
        __builtin_amdgcn_s_barrier();
        __builtin_amdgcn_sched_barrier(0);
#pragma unroll
        for (int mi = 0; mi < 4; ++mi) aR[mi]  = *(const bf16x8*)&Ac[base_a + mi * 128];
#pragma unroll
        for (int nj = 0; nj < 4; ++nj) bR0[nj] = *(const bf16x8*)&Bc[base_b + nj * 128];
        __builtin_amdgcn_s_setprio(1);
#pragma unroll
        for (int mi = 0; mi < 4; ++mi)
#pragma unroll
            for (int nj = 0; nj < 4; ++nj)
                acc[mi][nj] = __builtin_amdgcn_mfma_f32_16x16x32_bf16(aR[mi], bR0[nj], acc[mi][nj], 0, 0, 0);
        __builtin_amdgcn_s_setprio(0);
        __builtin_amdgcn_s_barrier();

        // ================= P1: stage A j2,j3; MFMA (kk0, mi4-7) =================
        if (t < 15) {
            gload_lds16(asrcb + kofs + 32, &Abuf[nxt][2 * 4096 + tid * 8]);
            gload_lds16(asrcb + kofs + 48, &Abuf[nxt][3 * 4096 + tid * 8]);
        }
#pragma unroll
        for (int mi = 0; mi < 4; ++mi) aR[mi] = *(const bf16x8*)&Ac[base_a + 512 + mi * 128];
        __builtin_amdgcn_s_setprio(1);
#pragma unroll
        for (int mi = 0; mi < 4; ++mi)
#pragma unroll
            for (int nj = 0; nj < 4; ++nj)
                acc[mi + 4][nj] = __builtin_amdgcn_mfma_f32_16x16x32_bf16(aR[mi], bR0[nj], acc[mi + 4][nj], 0, 0, 0);
        __builtin_amdgcn_s_setprio(0);
        __builtin_amdgcn_s_barrier();

        // ================= P2: stage B j0,j1; MFMA (kk1, mi0-3) =================
        if (t < 15) {
            gload_lds16(bsrcb + kofs,      &Bbuf[nxt][tid * 8]);
            gload_lds16(bsrcb + kofs + 16, &Bbuf[nxt][4096 + tid * 8]);
        }
#pragma unroll
        for (int mi = 0; mi < 4; ++mi) aR[mi]  = *(const bf16x8*)&Ac[base_a + 8192 + mi * 128];
#pragma unroll
        for (int nj = 0; nj < 4; ++nj) bR1[nj] = *(const bf16x8*)&Bc[base_b + 8192 + nj * 128];
        __builtin_amdgcn_s_setprio(1);
#pragma unroll
        for (int mi = 0; mi < 4; ++mi)
#pragma unroll
            for (int nj = 0; nj < 4; ++nj)
                acc[mi][nj] = __builtin_amdgcn_mfma_f32_16x16x32_bf16(aR[mi], bR1[nj], acc[mi][nj], 0, 0, 0);
        __builtin_amdgcn_s_setprio(0);
        __builtin_amdgcn_s_barrier();

        // ================= P3: stage B j2,j3; MFMA (kk1, mi4-7) =================
        if (t < 15) {
            gload_lds16(bsrcb + kofs + 32, &Bbuf[nxt][2 * 4096 + tid * 8]);
            gload_lds16(bsrcb + kofs + 48, &Bbuf[nxt][3 * 4096 + tid * 8]);
        }
#pragma unroll
        for (int mi = 0; mi < 4; ++mi) aR[mi] = *(const bf16x8*)&Ac[base_a + 8704 + mi * 128];
        __builtin_amdgcn_s_setprio(1);
#pragma unroll
        for (int mi = 0; mi < 4; ++mi)
#pragma unroll
            for (int nj = 0; nj < 4; ++nj)
                acc[mi + 4][nj] = __builtin_amdgcn_mfma_f32_16x16x32_bf16(aR[mi], bR1[nj], acc[mi + 4][nj], 0, 0, 0);
        __builtin_amdgcn_s_setprio(0);
        __builtin_amdgcn_s_barrier();
    }

    // ---- fused epilogue: tanh(x + qpb)*v, reduce over this block's 256 cols ----
    float rs[8][4];
#pragma unroll
    for (int mi = 0; mi < 8; ++mi)
#pragma unroll
        for (int r = 0; r < 4; ++r) rs[mi][r] = 0.f;

#pragma unroll
    for (int nj = 0; nj < 4; ++nj) {
        const int cl = wn * 64 + nj * 16 + colL;
        const float qadd = qv_lds[cl];
        const float vmul = vv_lds[cl];
#pragma unroll
        for (int mi = 0; mi < 8; ++mi)
#pragma unroll
            for (int r = 0; r < 4; ++r)
                rs[mi][r] += fast_tanh(acc[mi][nj][r] + qadd) * vmul;
    }
#pragma unroll
    for (int mi = 0; mi < 8; ++mi)
#pragma unroll
        for (int r = 0; r < 4; ++r) {
            float s = rs[mi][r];
            s += __shfl_xor(s, 1); s += __shfl_xor(s, 2);
            s += __shfl_xor(s, 4); s += __shfl_xor(s, 8);
            if (colL == 0) red[wn][wm * 128 + mi * 16 + grp * 4 + r] = s;
        }
    __syncthreads();
    if (tid < 256)
        spart[(size_t)nt * M_TOT + m0 + tid] =
            red[0][tid] + red[1][tid] + red[2][tid] + red[3][tid];
}

// ---------- fallback score kernel (fp32, no MFMA) ----------
__global__ __launch_bounds__(256)
void score_fallback_kernel(const float* __restrict__ values, const float* __restrict__ w2,
                           const float* __restrict__ qpb, const float* __restrict__ vvec,
                           float* __restrict__ spart) {
    int row0 = blockIdx.x * 16;
    int b = row0 >> 11;
    __shared__ float vr[16][D_DIM];
    for (int i = threadIdx.x; i < 16 * D_DIM; i += 256)
        vr[i >> 10][i & 1023] = values[(size_t)row0 * D_DIM + i];
    __syncthreads();
    float rs[16];
#pragma unroll
    for (int r = 0; r < 16; ++r) rs[r] = 0.f;
    for (int uu = threadIdx.x; uu < U_DIM; uu += 256) {
        float acc[16];
#pragma unroll
        for (int r = 0; r < 16; ++r) acc[r] = 0.f;
        for (int d = 0; d < D_DIM; ++d) {
            float wv = w2[(size_t)d * U_DIM + uu];
#pragma unroll
            for (int r = 0; r < 16; ++r) acc[r] += vr[r][d] * wv;
        }
        float qv = qpb[b * U_DIM + uu], vu = vvec[uu];
#pragma unroll
        for (int r = 0; r < 16; ++r) rs[r] += fast_tanh(acc[r] + qv) * vu;
    }
#pragma unroll
    for (int r = 0; r < 16; ++r) {
        float s = rs[r];
        for (int o = 1; o < 64; o <<= 1) s += __shfl_xor(s, o);
        rs[r] = s;
    }
    __shared__ float wred[16][4];
    int lane = threadIdx.x & 63, wid = threadIdx.x >> 6;
    if (lane == 0)
        for (int r = 0; r < 16; ++r) wred[r][wid] = rs[r];
    __syncthreads();
    if (threadIdx.x < 16)
        spart[row0 + threadIdx.x] = wred[threadIdx.x][0] + wred[threadIdx.x][1] +
                                    wred[threadIdx.x][2] + wred[threadIdx.x][3];
}

// ---------- kernel 3: masked softmax over S per batch ----------
__global__ void softmax_kernel(const float* __restrict__ spart, const int* __restrict__ mask,
                               float* __restrict__ wout, int nparts) {
    int b = blockIdx.x, t = threadIdx.x;
    float sc[8]; int mk[8];
    float mx = -1e30f;
#pragma unroll
    for (int i = 0; i < 8; ++i) {
        int s = t + i * 256;
        float vsum = 0.f;
        for (int p = 0; p < nparts; ++p) vsum += spart[(size_t)p * M_TOT + b * S_DIM + s];
        sc[i] = vsum;
        mk[i] = mask[b * S_DIM + s];
        if (mk[i]) mx = fmaxf(mx, vsum);
    }
    for (int o = 1; o < 64; o <<= 1) mx = fmaxf(mx, __shfl_xor(mx, o));
    __shared__ float red[4], red2[4];
    if ((t & 63) == 0) red[t >> 6] = mx;
    __syncthreads();
    mx = fmaxf(fmaxf(red[0], red[1]), fmaxf(red[2], red[3]));
    float sum = 0.f, ev[8];
#pragma unroll
    for (int i = 0; i < 8; ++i) {
        ev[i] = mk[i] ? __expf(sc[i] - mx) : 0.f;
        sum += ev[i];
    }
    for (int o = 1; o < 64; o <<= 1) sum += __shfl_xor(sum, o);
    if ((t & 63) == 0) red2[t >> 6] = sum;
    __syncthreads();
    sum = red2[0] + red2[1] + red2[2] + red2[3];
    float inv = 1.0f / sum;
#pragma unroll
    for (int i = 0; i < 8; ++i) wout[b * S_DIM + t + i * 256] = ev[i] * inv;
}

// ---------- kernel 4: context partial sums (bf16 values, 16B loads) ----------
// grid (32, 32), 128 threads: b, s-chunk of 64; thread t owns d in [t*8, t*8+8)
__global__ void ctx_partial_kernel(const u16* __restrict__ vbf, const float* __restrict__ w,
                                   float* __restrict__ part) {
    int b = blockIdx.x, c = blockIdx.y, t = threadIdx.x;
    const u16* vb = vbf + ((size_t)b * S_DIM + c * 64) * D_DIM + t * 8;
    const float* wb = w + b * S_DIM + c * 64;
    float acc[8];
#pragma unroll
    for (int i = 0; i < 8; ++i) acc[i] = 0.f;
    for (int s = 0; s < 64; ++s) {
        float wv = wb[s];
        u16x8 vv = *(const u16x8*)(vb + (size_t)s * D_DIM);
#pragma unroll
        for (int i = 0; i < 8; ++i) acc[i] += wv * bf2f(vv[i]);
    }
    float* pp = part + ((size_t)b * 32 + c) * D_DIM + t * 8;
#pragma unroll
    for (int i = 0; i < 8; ++i) pp[i] = acc[i];
}
// fp32 variant for fallback path
__global__ void ctx_partial_f32_kernel(const float* __restrict__ values, const float* __restrict__ w,
                                       float* __restrict__ part) {
    int b = blockIdx.x, c = blockIdx.y, t = threadIdx.x;
    const float4* vb = (const float4*)(values + ((size_t)b * S_DIM + c * 256) * D_DIM) + t;
    const float* wb = w + b * S_DIM + c * 256;
    float a0 = 0, a1 = 0, a2 = 0, a3 = 0;
    for (int s = 0; s < 256; ++s) {
        float wv = wb[s];
        float4 vv = vb[(size_t)s * 256];
        a0 += wv * vv.x; a1 += wv * vv.y; a2 += wv * vv.z; a3 += wv * vv.w;
    }
    float* pp = part + ((size_t)b * 8 + c) * D_DIM + t * 4;
    pp[0] = a0; pp[1] = a1; pp[2] = a2; pp[3] = a3;
}

// ---------- kernel 5: reduce context partials ----------
__global__ void ctx_reduce_kernel(const float* __restrict__ part, float* __restrict__ out, int nchunks) {
    int b = blockIdx.x, t = threadIdx.x;
    for (int d = t; d < D_DIM; d += 256) {
        float s = 0.f;
        for (int c = 0; c < nchunks; ++c) s += part[((size_t)b * nchunks + c) * D_DIM + d];
        out[b * D_DIM + d] = s;
    }
}

extern "C" void kernel_launch(void* const* d_in, const int* in_sizes, int n_in,
                              void* d_out, int out_size, void* d_ws, size_t ws_size,
                              hipStream_t stream) {
    const float* query  = (const float*)d_in[0];
    const float* values = (const float*)d_in[1];
    const int*   mask   = (const int*)d_in[2];
    const float* w1     = (const float*)d_in[3];
    const float* b1     = (const float*)d_in[4];
    const float* w2     = (const float*)d_in[5];
    const float* b2     = (const float*)d_in[6];
    const float* v      = (const float*)d_in[7];
    // bv (d_in[8]) shifts all scores equally -> softmax-invariant -> unused.

    float* out  = (float*)d_out;              // context [32][1024]
    float* wout = out + B_DIM * D_DIM;        // attention weights [32][2048]
    char* ws = (char*)d_ws;

    const size_t SZ_VBF = (size_t)M_TOT * D_DIM * 2;    // 134 MB bf16 values
    const size_t SZ_W2T = (size_t)U_DIM * D_DIM * 2;    // 2 MB
    const size_t SZ_QPB = (size_t)B_DIM * U_DIM * 4;    // 128 KB
    const size_t SZ_SPART = (size_t)8 * M_TOT * 4;      // 2 MB (4 used)
    const size_t SZ_PART  = (size_t)B_DIM * 32 * D_DIM * 4; // 4 MB
    const size_t need = SZ_VBF + SZ_W2T + SZ_QPB + SZ_SPART + SZ_PART;

    if (ws_size >= need) {
        u16*   vbf   = (u16*)ws;
        u16*   w2t   = (u16*)(ws + SZ_VBF);
        float* qpb   = (float*)(ws + SZ_VBF + SZ_W2T);
        float* spart = (float*)(ws + SZ_VBF + SZ_W2T + SZ_QPB);
        float* part  = (float*)(ws + SZ_VBF + SZ_W2T + SZ_QPB + SZ_SPART);

        convert_values_kernel<<<2048, 256, 0, stream>>>((const float4*)values, (ushort4*)vbf,
                                                        (long)M_TOT * D_DIM / 4);
        transpose_w2_kernel<<<dim3(32, 32), dim3(32, 8), 0, stream>>>(w2, w2t);
        qproj_kernel<<<32, 256, 0, stream>>>(query, w1, b1, b2, qpb);
        score_gemm8_kernel<<<1024, 512, 0, stream>>>(vbf, w2t, qpb, v, spart);
        softmax_kernel<<<32, 256, 0, stream>>>(spart, mask, wout, 4);
        ctx_partial_kernel<<<dim3(32, 32), 128, 0, stream>>>(vbf, wout, part);
        ctx_reduce_kernel<<<32, 256, 0, stream>>>(part, out, 32);
    } else {
        // conservative fp32 fallback (no big scratch available)
        float* qpb   = (float*)ws;
        float* spart = (float*)(ws + SZ_QPB);
        float* part  = (float*)(ws + SZ_QPB + (size_t)M_TOT * 4);
        qproj_kernel<<<32, 256, 0, stream>>>(query, w1, b1, b2, qpb);
        score_fallback_kernel<<<4096, 256, 0, stream>>>(values, w2, qpb, v, spart);
        softmax_kernel<<<32, 256, 0, stream>>>(spart, mask, wout, 1);
        ctx_partial_f32_kernel<<<dim3(32, 8), 256, 0, stream>>>(values, wout, part);
        ctx_reduce_kernel<<<32, 256, 0, stream>>>(part, out, 8);
    }
}

// Round 6
// 338.919 us; speedup vs baseline: 1.3211x; 1.3211x over previous
//
#include <hip/hip_runtime.h>
#include <cstdint>

typedef unsigned short u16;
typedef __bf16 bf16x8 __attribute__((ext_vector_type(8)));
typedef float f32x4 __attribute__((ext_vector_type(4)));

#define B_DIM 32
#define S_DIM 2048
#define D_DIM 1024
#define U_DIM 1024
#define M_TOT (B_DIM * S_DIM)   // 65536 rows

// ---------- helpers ----------
__device__ __forceinline__ u16 f2bf(float f) {
    union { float f; uint32_t u; } a; a.f = f;
    uint32_t u = a.u;
    uint32_t r = (u + 0x7FFFu + ((u >> 16) & 1u)) >> 16;   // RNE
    return (u16)r;
}
__device__ __forceinline__ float fast_tanh(float x) {
    float ax = fabsf(x);
    float e  = __expf(-2.0f * ax);
    float th = __fdividef(1.0f - e, 1.0f + e);
    return copysignf(th, x);
}
// global -> LDS async copy, 16B per lane
__device__ __forceinline__ void gload_lds16(const void* g, void* l) {
    __builtin_amdgcn_global_load_lds(
        (__attribute__((address_space(1))) void*)(uintptr_t)g,
        (__attribute__((address_space(3))) void*)(uint32_t)(uintptr_t)l,
        16, 0, 0);
}

// ---------- kernel 1b: w2 [D][U] f32 -> w2t [U][D] bf16 ----------
__global__ void transpose_w2_kernel(const float* __restrict__ w2, u16* __restrict__ w2t) {
    __shared__ float tile[32][33];
    int bx = blockIdx.x * 32, by = blockIdx.y * 32;
    int tx = threadIdx.x, ty = threadIdx.y;  // (32, 8)
    for (int i = 0; i < 32; i += 8)
        tile[ty + i][tx] = w2[(size_t)(by + ty + i) * U_DIM + bx + tx];
    __syncthreads();
    for (int i = 0; i < 32; i += 8)
        w2t[(size_t)(bx + ty + i) * D_DIM + by + tx] = f2bf(tile[tx][ty + i]);
}

// ---------- kernel 1c: qpb[b][u] = query@w1 + b1 + b2 (fp32) ----------
__global__ void qproj_kernel(const float* __restrict__ q, const float* __restrict__ w1,
                             const float* __restrict__ b1, const float* __restrict__ b2,
                             float* __restrict__ qpb) {
    int b = blockIdx.x;
    int u = blockIdx.y * 256 + threadIdx.x;
    __shared__ float ql[D_DIM];
    for (int d = threadIdx.x; d < D_DIM; d += 256) ql[d] = q[b * D_DIM + d];
    __syncthreads();
    float acc = b1[u] + b2[u];
    for (int d = 0; d < D_DIM; ++d) acc += ql[d] * w1[(size_t)d * U_DIM + u];
    qpb[b * U_DIM + u] = acc;
}

// ---------- kernel 2: 256x256-tile, 8-wave, 4-phase/K-tile GEMM ----------
// Round-3 skeleton (174us proven). A-path fused: reg-stage f32 values,
// convert to bf16 in-register, ds_write into the SAME swizzled LDS image
// the old pre-swizzled-source global_load_lds produced. B-path unchanged.
__global__ __launch_bounds__(512, 2)
void score_gemm8_kernel(const float* __restrict__ vals, const u16* __restrict__ w2t,
                        const float* __restrict__ qpb, const float* __restrict__ vvec,
                        float* __restrict__ spart) {
    const int p    = blockIdx.x;
    const int xcd  = p & 7;
    const int slot = p >> 3;
    const int mt   = xcd * 32 + (slot >> 2);   // 0..255
    const int nt   = slot & 3;                 // 0..3
    const int m0 = mt * 256;
    const int n0 = nt * 256;
    const int b  = m0 >> 11;

    __shared__ __align__(16) __bf16 Abuf[2][256 * 64];   // 64 KB
    __shared__ __align__(16) __bf16 Bbuf[2][256 * 64];   // 64 KB
    __shared__ float qv_lds[256], vv_lds[256];
    __shared__ float red[4][256];

    const int tid  = threadIdx.x;
    const int lane = tid & 63;
    const int wid  = tid >> 6;     // 0..7
    const int wm   = wid >> 2;     // 0..1  (M split)
    const int wn   = wid & 3;      // 0..3  (N split)

    if (tid < 256) qv_lds[tid] = qpb[b * U_DIM + n0 + tid];
    else           vv_lds[tid - 256] = vvec[n0 + (tid - 256)];

    // B staging (unchanged): pre-swizzled source col, linear LDS dest
    const int tr = tid >> 3;                              // 0..63 (row within issue)
    const int sc = (((tid & 7) ^ (tr & 7)) << 3);         // swizzled source col (elems)
    const u16* bsrc = w2t + (size_t)(n0 + tr) * D_DIM + sc;

    // A staging (fused cvt): UNswizzled coalesced f32 source, swizzled LDS write.
    // LDS[row][oct] must hold global octet (oct ^ (row&7)) -> we load octet
    // g=(tid&7) and write it at oct = g ^ (row&7), row = j*64 + tr.
    const float* asrc = vals + (size_t)(m0 + tr) * D_DIM + (tid & 7) * 8;
    const int awo = tr * 64 + (((tid & 7) ^ (tr & 7)) << 3);   // write elem offset within j-block

    float4 aF[4][2];

    // ---- prologue: stage K-tile 0 into buffer 0 ----
#pragma unroll
    for (int j = 0; j < 4; ++j) {
        aF[j][0] = *(const float4*)(asrc + (size_t)j * 64 * D_DIM);
        aF[j][1] = *(const float4*)(asrc + (size_t)j * 64 * D_DIM + 4);
    }
#pragma unroll
    for (int j = 0; j < 4; ++j)
        gload_lds16(bsrc + (size_t)j * 64 * D_DIM, &Bbuf[0][j * 4096 + tid * 8]);
#pragma unroll
    for (int j = 0; j < 4; ++j) {
        bf16x8 h;
#pragma unroll
        for (int i = 0; i < 4; ++i) { h[i] = (__bf16)aF[j][0][i]; h[i + 4] = (__bf16)aF[j][1][i]; }
        *(bf16x8*)&Abuf[0][j * 4096 + awo] = h;
    }

    f32x4 acc[8][4];
#pragma unroll
    for (int mi = 0; mi < 8; ++mi)
#pragma unroll
        for (int nj = 0; nj < 4; ++nj) acc[mi][nj] = (f32x4){0.f, 0.f, 0.f, 0.f};

    const int colL = lane & 15;
    const int grp  = lane >> 4;
    const int xork = (lane & 7) << 3;
    const int kix0 = (grp * 8) ^ xork;        // kk=0 swizzled col
    const int kix1 = ((32 + grp * 8)) ^ xork; // kk=1 swizzled col
    const int arow = wm * 128 + colL;
    const int brow = wn * 64 + colL;

    bf16x8 aR[4], bR0[4], bR1[4];

    for (int t = 0; t < 16; ++t) {
        const int cur = t & 1, nxt = cur ^ 1;
        const __bf16* Ac = Abuf[cur];
        const __bf16* Bc = Bbuf[cur];
        const size_t kofs = (size_t)(t + 1) * 64;

        // ---- P0 head: issue A-reg loads for t+1, then publish tile t ----
        // outstanding before issue: 4 B-gloads (tile t). vmcnt(8) exempts the
        // 8 fresh A loads, drains B. lgkmcnt(0) publishes t-1's A ds_writes.
        if (t < 15) {
#pragma unroll
            for (int j = 0; j < 4; ++j) {
                aF[j][0] = *(const float4*)(asrc + kofs + (size_t)j * 64 * D_DIM);
                aF[j][1] = *(const float4*)(asrc + kofs + (size_t)j * 64 * D_DIM + 4);
            }
            __builtin_amdgcn_sched_barrier(0);   // pin load issues above the wait
            asm volatile("s_waitcnt vmcnt(8) lgkmcnt(0)" ::: "memory");
        } else {
            asm volatile("s_waitcnt vmcnt(0) lgkmcnt(0)" ::: "memory");
        }
        __builtin_amdgcn_s_barrier();
        __builtin_amdgcn_sched_barrier(0);

        // ================= P0: MFMA (kk0, mi0-3) =================
#pragma unroll
        for (int mi = 0; mi < 4; ++mi) aR[mi]  = *(const bf16x8*)&Ac[(arow + mi * 16) * 64 + kix0];
#pragma unroll
        for (int nj = 0; nj < 4; ++nj) bR0[nj] = *(const bf16x8*)&Bc[(brow + nj * 16) * 64 + kix0];
        __builtin_amdgcn_s_setprio(1);
#pragma unroll
        for (int mi = 0; mi < 4; ++mi)
#pragma unroll
            for (int nj = 0; nj < 4; ++nj)
                acc[mi][nj] = __builtin_amdgcn_mfma_f32_16x16x32_bf16(aR[mi], bR0[nj], acc[mi][nj], 0, 0, 0);
        __builtin_amdgcn_s_setprio(0);
        __builtin_amdgcn_s_barrier();

        // ================= P1: MFMA (kk0, mi4-7) =================
#pragma unroll
        for (int mi = 0; mi < 4; ++mi) aR[mi] = *(const bf16x8*)&Ac[(arow + 64 + mi * 16) * 64 + kix0];
        __builtin_amdgcn_s_setprio(1);
#pragma unroll
        for (int mi = 0; mi < 4; ++mi)
#pragma unroll
            for (int nj = 0; nj < 4; ++nj)
                acc[mi + 4][nj] = __builtin_amdgcn_mfma_f32_16x16x32_bf16(aR[mi], bR0[nj], acc[mi + 4][nj], 0, 0, 0);
        __builtin_amdgcn_s_setprio(0);
        __builtin_amdgcn_s_barrier();

        // ================= P2: stage B j0,j1 (t+1); MFMA (kk1, mi0-3) =================
        if (t < 15) {
            gload_lds16(bsrc + kofs,                   &Bbuf[nxt][tid * 8]);
            gload_lds16(bsrc + kofs + (size_t)65536,   &Bbuf[nxt][4096 + tid * 8]);
        }
#pragma unroll
        for (int mi = 0; mi < 4; ++mi) aR[mi]  = *(const bf16x8*)&Ac[(arow + mi * 16) * 64 + kix1];
#pragma unroll
        for (int nj = 0; nj < 4; ++nj) bR1[nj] = *(const bf16x8*)&Bc[(brow + nj * 16) * 64 + kix1];
        __builtin_amdgcn_s_setprio(1);
#pragma unroll
        for (int mi = 0; mi < 4; ++mi)
#pragma unroll
            for (int nj = 0; nj < 4; ++nj)
                acc[mi][nj] = __builtin_amdgcn_mfma_f32_16x16x32_bf16(aR[mi], bR1[nj], acc[mi][nj], 0, 0, 0);
        __builtin_amdgcn_s_setprio(0);
        __builtin_amdgcn_s_barrier();

        // ================= P3: stage B j2,j3; MFMA (kk1, mi4-7); cvt+write A(t+1) ======
        if (t < 15) {
            gload_lds16(bsrc + kofs + (size_t)2 * 65536, &Bbuf[nxt][2 * 4096 + tid * 8]);
            gload_lds16(bsrc + kofs + (size_t)3 * 65536, &Bbuf[nxt][3 * 4096 + tid * 8]);
        }
#pragma unroll
        for (int mi = 0; mi < 4; ++mi) aR[mi] = *(const bf16x8*)&Ac[(arow + 64 + mi * 16) * 64 + kix1];
        __builtin_amdgcn_s_setprio(1);
#pragma unroll
        for (int mi = 0; mi < 4; ++mi)
#pragma unroll
            for (int nj = 0; nj < 4; ++nj)
                acc[mi + 4][nj] = __builtin_amdgcn_mfma_f32_16x16x32_bf16(aR[mi], bR1[nj], acc[mi + 4][nj], 0, 0, 0);
        __builtin_amdgcn_s_setprio(0);
        if (t < 15) {
            // compiler inserts the vmcnt wait for aF (4 B-gloads stay in flight)
#pragma unroll
            for (int j = 0; j < 4; ++j) {
                bf16x8 h;
#pragma unroll
                for (int i = 0; i < 4; ++i) { h[i] = (__bf16)aF[j][0][i]; h[i + 4] = (__bf16)aF[j][1][i]; }
                *(bf16x8*)&Abuf[nxt][j * 4096 + awo] = h;
            }
        }
        __builtin_amdgcn_s_barrier();
    }

    // ---- fused epilogue: tanh(x + qpb)*v, reduce over this block's 256 cols ----
    float rs[8][4];
#pragma unroll
    for (int mi = 0; mi < 8; ++mi)
#pragma unroll
        for (int r = 0; r < 4; ++r) rs[mi][r] = 0.f;

#pragma unroll
    for (int nj = 0; nj < 4; ++nj) {
        const int cl = wn * 64 + nj * 16 + colL;
        const float qadd = qv_lds[cl];
        const float vmul = vv_lds[cl];
#pragma unroll
        for (int mi = 0; mi < 8; ++mi)
#pragma unroll
            for (int r = 0; r < 4; ++r)
                rs[mi][r] += fast_tanh(acc[mi][nj][r] + qadd) * vmul;
    }
#pragma unroll
    for (int mi = 0; mi < 8; ++mi)
#pragma unroll
        for (int r = 0; r < 4; ++r) {
            float s = rs[mi][r];
            s += __shfl_xor(s, 1); s += __shfl_xor(s, 2);
            s += __shfl_xor(s, 4); s += __shfl_xor(s, 8);
            if (colL == 0) red[wn][wm * 128 + mi * 16 + grp * 4 + r] = s;
        }
    __syncthreads();
    if (tid < 256)
        spart[(size_t)nt * M_TOT + m0 + tid] =
            red[0][tid] + red[1][tid] + red[2][tid] + red[3][tid];
}

// ---------- fallback score kernel (fp32, no MFMA) ----------
__global__ __launch_bounds__(256)
void score_fallback_kernel(const float* __restrict__ values, const float* __restrict__ w2,
                           const float* __restrict__ qpb, const float* __restrict__ vvec,
                           float* __restrict__ spart) {
    int row0 = blockIdx.x * 16;
    int b = row0 >> 11;
    __shared__ float vr[16][D_DIM];
    for (int i = threadIdx.x; i < 16 * D_DIM; i += 256)
        vr[i >> 10][i & 1023] = values[(size_t)row0 * D_DIM + i];
    __syncthreads();
    float rs[16];
#pragma unroll
    for (int r = 0; r < 16; ++r) rs[r] = 0.f;
    for (int uu = threadIdx.x; uu < U_DIM; uu += 256) {
        float acc[16];
#pragma unroll
        for (int r = 0; r < 16; ++r) acc[r] = 0.f;
        for (int d = 0; d < D_DIM; ++d) {
            float wv = w2[(size_t)d * U_DIM + uu];
#pragma unroll
            for (int r = 0; r < 16; ++r) acc[r] += vr[r][d] * wv;
        }
        float qv = qpb[b * U_DIM + uu], vu = vvec[uu];
#pragma unroll
        for (int r = 0; r < 16; ++r) rs[r] += fast_tanh(acc[r] + qv) * vu;
    }
#pragma unroll
    for (int r = 0; r < 16; ++r) {
        float s = rs[r];
        for (int o = 1; o < 64; o <<= 1) s += __shfl_xor(s, o);
        rs[r] = s;
    }
    __shared__ float wred[16][4];
    int lane = threadIdx.x & 63, wid = threadIdx.x >> 6;
    if (lane == 0)
        for (int r = 0; r < 16; ++r) wred[r][wid] = rs[r];
    __syncthreads();
    if (threadIdx.x < 16)
        spart[row0 + threadIdx.x] = wred[threadIdx.x][0] + wred[threadIdx.x][1] +
                                    wred[threadIdx.x][2] + wred[threadIdx.x][3];
}

// ---------- kernel 3: masked softmax over S per batch ----------
__global__ void softmax_kernel(const float* __restrict__ spart, const int* __restrict__ mask,
                               float* __restrict__ wout, int nparts) {
    int b = blockIdx.x, t = threadIdx.x;
    float sc[8]; int mk[8];
    float mx = -1e30f;
#pragma unroll
    for (int i = 0; i < 8; ++i) {
        int s = t + i * 256;
        float vsum = 0.f;
        for (int p = 0; p < nparts; ++p) vsum += spart[(size_t)p * M_TOT + b * S_DIM + s];
        sc[i] = vsum;
        mk[i] = mask[b * S_DIM + s];
        if (mk[i]) mx = fmaxf(mx, vsum);
    }
    for (int o = 1; o < 64; o <<= 1) mx = fmaxf(mx, __shfl_xor(mx, o));
    __shared__ float red[4], red2[4];
    if ((t & 63) == 0) red[t >> 6] = mx;
    __syncthreads();
    mx = fmaxf(fmaxf(red[0], red[1]), fmaxf(red[2], red[3]));
    float sum = 0.f, ev[8];
#pragma unroll
    for (int i = 0; i < 8; ++i) {
        ev[i] = mk[i] ? __expf(sc[i] - mx) : 0.f;
        sum += ev[i];
    }
    for (int o = 1; o < 64; o <<= 1) sum += __shfl_xor(sum, o);
    if ((t & 63) == 0) red2[t >> 6] = sum;
    __syncthreads();
    sum = red2[0] + red2[1] + red2[2] + red2[3];
    float inv = 1.0f / sum;
#pragma unroll
    for (int i = 0; i < 8; ++i) wout[b * S_DIM + t + i * 256] = ev[i] * inv;
}

// ---------- kernel 4: context partial sums (f32 values, float4 loads) ----------
// grid (32, 16), 256 threads: b, s-chunk of 128; thread t owns d in [t*4, t*4+4)
__global__ void ctx_partial_f32_kernel(const float* __restrict__ values, const float* __restrict__ w,
                                       float* __restrict__ part) {
    int b = blockIdx.x, c = blockIdx.y, t = threadIdx.x;
    const float4* vb = (const float4*)(values + ((size_t)b * S_DIM + c * 128) * D_DIM) + t;
    const float* wb = w + b * S_DIM + c * 128;
    float a0 = 0, a1 = 0, a2 = 0, a3 = 0;
    for (int s = 0; s < 128; ++s) {
        float wv = wb[s];
        float4 vv = vb[(size_t)s * 256];
        a0 += wv * vv.x; a1 += wv * vv.y; a2 += wv * vv.z; a3 += wv * vv.w;
    }
    float* pp = part + ((size_t)b * 16 + c) * D_DIM + t * 4;
    pp[0] = a0; pp[1] = a1; pp[2] = a2; pp[3] = a3;
}

// ---------- kernel 5: reduce context partials ----------
__global__ void ctx_reduce_kernel(const float* __restrict__ part, float* __restrict__ out, int nchunks) {
    int b = blockIdx.x, t = threadIdx.x;
    for (int d = t; d < D_DIM; d += 256) {
        float s = 0.f;
        for (int c = 0; c < nchunks; ++c) s += part[((size_t)b * nchunks + c) * D_DIM + d];
        out[b * D_DIM + d] = s;
    }
}

extern "C" void kernel_launch(void* const* d_in, const int* in_sizes, int n_in,
                              void* d_out, int out_size, void* d_ws, size_t ws_size,
                              hipStream_t stream) {
    const float* query  = (const float*)d_in[0];
    const float* values = (const float*)d_in[1];
    const int*   mask   = (const int*)d_in[2];
    const float* w1     = (const float*)d_in[3];
    const float* b1     = (const float*)d_in[4];
    const float* w2     = (const float*)d_in[5];
    const float* b2     = (const float*)d_in[6];
    const float* v      = (const float*)d_in[7];
    // bv (d_in[8]) shifts all scores equally -> softmax-invariant -> unused.

    float* out  = (float*)d_out;              // context [32][1024]
    float* wout = out + B_DIM * D_DIM;        // attention weights [32][2048]
    char* ws = (char*)d_ws;

    const size_t SZ_W2T = (size_t)U_DIM * D_DIM * 2;        // 2 MB
    const size_t SZ_QPB = (size_t)B_DIM * U_DIM * 4;        // 128 KB
    const size_t SZ_SPART = (size_t)4 * M_TOT * 4;          // 1 MB
    const size_t SZ_PART  = (size_t)B_DIM * 16 * D_DIM * 4; // 2 MB
    const size_t need = SZ_W2T + SZ_QPB + SZ_SPART + SZ_PART;

    if (ws_size >= need) {
        u16*   w2t   = (u16*)ws;
        float* qpb   = (float*)(ws + SZ_W2T);
        float* spart = (float*)(ws + SZ_W2T + SZ_QPB);
        float* part  = (float*)(ws + SZ_W2T + SZ_QPB + SZ_SPART);

        transpose_w2_kernel<<<dim3(32, 32), dim3(32, 8), 0, stream>>>(w2, w2t);
        qproj_kernel<<<dim3(32, 4), 256, 0, stream>>>(query, w1, b1, b2, qpb);
        score_gemm8_kernel<<<1024, 512, 0, stream>>>(values, w2t, qpb, v, spart);
        softmax_kernel<<<32, 256, 0, stream>>>(spart, mask, wout, 4);
        ctx_partial_f32_kernel<<<dim3(32, 16), 256, 0, stream>>>(values, wout, part);
        ctx_reduce_kernel<<<32, 256, 0, stream>>>(part, out, 16);
    } else {
        // conservative fp32 fallback (no big scratch available)
        float* qpb   = (float*)ws;
        float* spart = (float*)(ws + SZ_QPB);
        float* part  = (float*)(ws + SZ_QPB + (size_t)M_TOT * 4);
        qproj_kernel<<<dim3(32, 4), 256, 0, stream>>>(query, w1, b1, b2, qpb);
        score_fallback_kernel<<<4096, 256, 0, stream>>>(values, w2, qpb, v, spart);
        softmax_kernel<<<32, 256, 0, stream>>>(spart, mask, wout, 1);
        ctx_partial_f32_kernel<<<dim3(32, 16), 256, 0, stream>>>(values, wout, part);
        ctx_reduce_kernel<<<32, 256, 0, stream>>>(part, out, 16);
    }
}

// Round 7
// 338.131 us; speedup vs baseline: 1.3242x; 1.0023x over previous
//
#include <hip/hip_runtime.h>
#include <cstdint>

typedef unsigned short u16;
typedef __bf16 bf16x8 __attribute__((ext_vector_type(8)));
typedef float f32x4 __attribute__((ext_vector_type(4)));
typedef u16 u16x8 __attribute__((ext_vector_type(8)));

#define B_DIM 32
#define S_DIM 2048
#define D_DIM 1024
#define U_DIM 1024
#define M_TOT (B_DIM * S_DIM)   // 65536 rows

// ---------- helpers ----------
__device__ __forceinline__ u16 f2bf(float f) {
    union { float f; uint32_t u; } a; a.f = f;
    uint32_t u = a.u;
    uint32_t r = (u + 0x7FFFu + ((u >> 16) & 1u)) >> 16;   // RNE
    return (u16)r;
}
__device__ __forceinline__ float bf2f(u16 h) {
    union { uint32_t u; float f; } a; a.u = ((uint32_t)h) << 16;
    return a.f;
}
__device__ __forceinline__ float fast_tanh(float x) {
    float ax = fabsf(x);
    float e  = __expf(-2.0f * ax);
    float th = __fdividef(1.0f - e, 1.0f + e);
    return copysignf(th, x);
}
// global -> LDS async copy, 16B per lane
__device__ __forceinline__ void gload_lds16(const void* g, void* l) {
    __builtin_amdgcn_global_load_lds(
        (__attribute__((address_space(1))) void*)(uintptr_t)g,
        (__attribute__((address_space(3))) void*)(uint32_t)(uintptr_t)l,
        16, 0, 0);
}

// ---------- kernel 1a: values f32 -> bf16 ----------
__global__ void convert_values_kernel(const float4* __restrict__ in, ushort4* __restrict__ out, long n4) {
    long i = (long)blockIdx.x * blockDim.x + threadIdx.x;
    long stride = (long)gridDim.x * blockDim.x;
    for (; i < n4; i += stride) {
        float4 v = in[i];
        ushort4 o;
        o.x = f2bf(v.x); o.y = f2bf(v.y); o.z = f2bf(v.z); o.w = f2bf(v.w);
        out[i] = o;
    }
}

// ---------- kernel 1b: w2 [D][U] f32 -> w2t [U][D] bf16 ----------
__global__ void transpose_w2_kernel(const float* __restrict__ w2, u16* __restrict__ w2t) {
    __shared__ float tile[32][33];
    int bx = blockIdx.x * 32, by = blockIdx.y * 32;
    int tx = threadIdx.x, ty = threadIdx.y;  // (32, 8)
    for (int i = 0; i < 32; i += 8)
        tile[ty + i][tx] = w2[(size_t)(by + ty + i) * U_DIM + bx + tx];
    __syncthreads();
    for (int i = 0; i < 32; i += 8)
        w2t[(size_t)(bx + ty + i) * D_DIM + by + tx] = f2bf(tile[tx][ty + i]);
}

// ---------- kernel 1c: qpb[b][u] = query@w1 + b1 + b2 (fp32) ----------
__global__ void qproj_kernel(const float* __restrict__ q, const float* __restrict__ w1,
                             const float* __restrict__ b1, const float* __restrict__ b2,
                             float* __restrict__ qpb) {
    int b = blockIdx.x;
    int u = blockIdx.y * 256 + threadIdx.x;
    __shared__ float ql[D_DIM];
    for (int d = threadIdx.x; d < D_DIM; d += 256) ql[d] = q[b * D_DIM + d];
    __syncthreads();
    float acc = b1[u] + b2[u];
    for (int d = 0; d < D_DIM; ++d) acc += ql[d] * w1[(size_t)d * U_DIM + u];
    qpb[b * U_DIM + u] = acc;
}

// ---------- kernel 2: 256x256-tile, 8-wave, 4-phase/K-tile, counted-vmcnt GEMM ----------
// Round-3 skeleton. Staging spread: P0 stages ALL A of t+1 (vmcnt(4) counted wait),
// P1 stages B01, P2 stages B23, P3 stages nothing -> youngest loads get 2 phases
// of slack (was 1), A gets 4. Wait never drains to 0 mid-loop.
__global__ __launch_bounds__(512, 2)
void score_gemm8_kernel(const u16* __restrict__ vbf, const u16* __restrict__ w2t,
                        const float* __restrict__ qpb, const float* __restrict__ vvec,
                        float* __restrict__ spart) {
    const int p    = blockIdx.x;
    const int xcd  = p & 7;
    const int slot = p >> 3;
    const int mt   = xcd * 32 + (slot >> 2);   // 0..255
    const int nt   = slot & 3;                 // 0..3
    const int m0 = mt * 256;
    const int n0 = nt * 256;
    const int b  = m0 >> 11;

    __shared__ __align__(16) __bf16 Abuf[2][256 * 64];   // 64 KB
    __shared__ __align__(16) __bf16 Bbuf[2][256 * 64];   // 64 KB
    __shared__ float qv_lds[256], vv_lds[256];
    __shared__ float red[4][256];

    const int tid  = threadIdx.x;
    const int lane = tid & 63;
    const int wid  = tid >> 6;     // 0..7
    const int wm   = wid >> 2;     // 0..1  (M split)
    const int wn   = wid & 3;      // 0..3  (N split)

    if (tid < 256) qv_lds[tid] = qpb[b * U_DIM + n0 + tid];
    else           vv_lds[tid - 256] = vvec[n0 + (tid - 256)];

    // staging: thread t -> LDS linear bytes [t*16, t*16+16) (+ j*4096 per issue)
    // source column pre-swizzled so that LDS holds the XOR-swizzled layout
    const int tr = tid >> 3;                              // 0..63 (row within issue)
    const int sc = (((tid & 7) ^ (tr & 7)) << 3);         // swizzled source col (elems)
    const u16* asrc = vbf + (size_t)(m0 + tr) * D_DIM + sc;
    const u16* bsrc = w2t + (size_t)(n0 + tr) * D_DIM + sc;

    // prologue: stage K-tile 0 into buffer 0
#pragma unroll
    for (int j = 0; j < 4; ++j) {
        gload_lds16(asrc + (size_t)j * 64 * D_DIM, &Abuf[0][j * 4096 + tid * 8]);
        gload_lds16(bsrc + (size_t)j * 64 * D_DIM, &Bbuf[0][j * 4096 + tid * 8]);
    }

    f32x4 acc[8][4];
#pragma unroll
    for (int mi = 0; mi < 8; ++mi)
#pragma unroll
        for (int nj = 0; nj < 4; ++nj) acc[mi][nj] = (f32x4){0.f, 0.f, 0.f, 0.f};

    const int colL = lane & 15;
    const int grp  = lane >> 4;
    const int xork = (lane & 7) << 3;
    const int kix0 = (grp * 8) ^ xork;        // kk=0 swizzled col
    const int kix1 = ((32 + grp * 8)) ^ xork; // kk=1 swizzled col
    const int arow = wm * 128 + colL;
    const int brow = wn * 64 + colL;

    bf16x8 aR[4], bR0[4], bR1[4];

    for (int t = 0; t < 16; ++t) {
        const int cur = t & 1, nxt = cur ^ 1;
        const __bf16* Ac = Abuf[cur];
        const __bf16* Bc = Bbuf[cur];
        const size_t kofs = (size_t)(t + 1) * 64;

        // ====== P0: stage ALL A of t+1; counted wait for tile t; MFMA (kk0, mi0-3) ======
        if (t < 15) {
            gload_lds16(asrc + kofs,                     &Abuf[nxt][tid * 8]);
            gload_lds16(asrc + kofs + (size_t)65536,     &Abuf[nxt][4096 + tid * 8]);
            gload_lds16(asrc + kofs + (size_t)2 * 65536, &Abuf[nxt][2 * 4096 + tid * 8]);
            gload_lds16(asrc + kofs + (size_t)3 * 65536, &Abuf[nxt][3 * 4096 + tid * 8]);
            asm volatile("s_waitcnt vmcnt(4)" ::: "memory");   // drain tile t; exempt fresh A
        } else {
            asm volatile("s_waitcnt vmcnt(0)" ::: "memory");
        }
        __builtin_amdgcn_s_barrier();
        __builtin_amdgcn_sched_barrier(0);
#pragma unroll
        for (int mi = 0; mi < 4; ++mi) aR[mi]  = *(const bf16x8*)&Ac[(arow + mi * 16) * 64 + kix0];
#pragma unroll
        for (int nj = 0; nj < 4; ++nj) bR0[nj] = *(const bf16x8*)&Bc[(brow + nj * 16) * 64 + kix0];
        __builtin_amdgcn_s_setprio(1);
#pragma unroll
        for (int mi = 0; mi < 4; ++mi)
#pragma unroll
            for (int nj = 0; nj < 4; ++nj)
                acc[mi][nj] = __builtin_amdgcn_mfma_f32_16x16x32_bf16(aR[mi], bR0[nj], acc[mi][nj], 0, 0, 0);
        __builtin_amdgcn_s_setprio(0);
        __builtin_amdgcn_s_barrier();

        // ================= P1: stage B j0,j1; MFMA (kk0, mi4-7) =================
        if (t < 15) {
            gload_lds16(bsrc + kofs,                   &Bbuf[nxt][tid * 8]);
            gload_lds16(bsrc + kofs + (size_t)65536,   &Bbuf[nxt][4096 + tid * 8]);
        }
#pragma unroll
        for (int mi = 0; mi < 4; ++mi) aR[mi] = *(const bf16x8*)&Ac[(arow + 64 + mi * 16) * 64 + kix0];
        __builtin_amdgcn_s_setprio(1);
#pragma unroll
        for (int mi = 0; mi < 4; ++mi)
#pragma unroll
            for (int nj = 0; nj < 4; ++nj)
                acc[mi + 4][nj] = __builtin_amdgcn_mfma_f32_16x16x32_bf16(aR[mi], bR0[nj], acc[mi + 4][nj], 0, 0, 0);
        __builtin_amdgcn_s_setprio(0);
        __builtin_amdgcn_s_barrier();

        // ================= P2: stage B j2,j3; MFMA (kk1, mi0-3) =================
        if (t < 15) {
            gload_lds16(bsrc + kofs + (size_t)2 * 65536, &Bbuf[nxt][2 * 4096 + tid * 8]);
            gload_lds16(bsrc + kofs + (size_t)3 * 65536, &Bbuf[nxt][3 * 4096 + tid * 8]);
        }
#pragma unroll
        for (int mi = 0; mi < 4; ++mi) aR[mi]  = *(const bf16x8*)&Ac[(arow + mi * 16) * 64 + kix1];
#pragma unroll
        for (int nj = 0; nj < 4; ++nj) bR1[nj] = *(const bf16x8*)&Bc[(brow + nj * 16) * 64 + kix1];
        __builtin_amdgcn_s_setprio(1);
#pragma unroll
        for (int mi = 0; mi < 4; ++mi)
#pragma unroll
            for (int nj = 0; nj < 4; ++nj)
                acc[mi][nj] = __builtin_amdgcn_mfma_f32_16x16x32_bf16(aR[mi], bR1[nj], acc[mi][nj], 0, 0, 0);
        __builtin_amdgcn_s_setprio(0);
        __builtin_amdgcn_s_barrier();

        // ================= P3: MFMA (kk1, mi4-7) =================
#pragma unroll
        for (int mi = 0; mi < 4; ++mi) aR[mi] = *(const bf16x8*)&Ac[(arow + 64 + mi * 16) * 64 + kix1];
        __builtin_amdgcn_s_setprio(1);
#pragma unroll
        for (int mi = 0; mi < 4; ++mi)
#pragma unroll
            for (int nj = 0; nj < 4; ++nj)
                acc[mi + 4][nj] = __builtin_amdgcn_mfma_f32_16x16x32_bf16(aR[mi], bR1[nj], acc[mi + 4][nj], 0, 0, 0);
        __builtin_amdgcn_s_setprio(0);
        __builtin_amdgcn_s_barrier();
    }

    // ---- fused epilogue: tanh(x + qpb)*v, reduce over this block's 256 cols ----
    float rs[8][4];
#pragma unroll
    for (int mi = 0; mi < 8; ++mi)
#pragma unroll
        for (int r = 0; r < 4; ++r) rs[mi][r] = 0.f;

#pragma unroll
    for (int nj = 0; nj < 4; ++nj) {
        const int cl = wn * 64 + nj * 16 + colL;
        const float qadd = qv_lds[cl];
        const float vmul = vv_lds[cl];
#pragma unroll
        for (int mi = 0; mi < 8; ++mi)
#pragma unroll
            for (int r = 0; r < 4; ++r)
                rs[mi][r] += fast_tanh(acc[mi][nj][r] + qadd) * vmul;
    }
#pragma unroll
    for (int mi = 0; mi < 8; ++mi)
#pragma unroll
        for (int r = 0; r < 4; ++r) {
            float s = rs[mi][r];
            s += __shfl_xor(s, 1); s += __shfl_xor(s, 2);
            s += __shfl_xor(s, 4); s += __shfl_xor(s, 8);
            if (colL == 0) red[wn][wm * 128 + mi * 16 + grp * 4 + r] = s;
        }
    __syncthreads();
    if (tid < 256)
        spart[(size_t)nt * M_TOT + m0 + tid] =
            red[0][tid] + red[1][tid] + red[2][tid] + red[3][tid];
}

// ---------- fallback score kernel (fp32, no MFMA) ----------
__global__ __launch_bounds__(256)
void score_fallback_kernel(const float* __restrict__ values, const float* __restrict__ w2,
                           const float* __restrict__ qpb, const float* __restrict__ vvec,
                           float* __restrict__ spart) {
    int row0 = blockIdx.x * 16;
    int b = row0 >> 11;
    __shared__ float vr[16][D_DIM];
    for (int i = threadIdx.x; i < 16 * D_DIM; i += 256)
        vr[i >> 10][i & 1023] = values[(size_t)row0 * D_DIM + i];
    __syncthreads();
    float rs[16];
#pragma unroll
    for (int r = 0; r < 16; ++r) rs[r] = 0.f;
    for (int uu = threadIdx.x; uu < U_DIM; uu += 256) {
        float acc[16];
#pragma unroll
        for (int r = 0; r < 16; ++r) acc[r] = 0.f;
        for (int d = 0; d < D_DIM; ++d) {
            float wv = w2[(size_t)d * U_DIM + uu];
#pragma unroll
            for (int r = 0; r < 16; ++r) acc[r] += vr[r][d] * wv;
        }
        float qv = qpb[b * U_DIM + uu], vu = vvec[uu];
#pragma unroll
        for (int r = 0; r < 16; ++r) rs[r] += fast_tanh(acc[r] + qv) * vu;
    }
#pragma unroll
    for (int r = 0; r < 16; ++r) {
        float s = rs[r];
        for (int o = 1; o < 64; o <<= 1) s += __shfl_xor(s, o);
        rs[r] = s;
    }
    __shared__ float wred[16][4];
    int lane = threadIdx.x & 63, wid = threadIdx.x >> 6;
    if (lane == 0)
        for (int r = 0; r < 16; ++r) wred[r][wid] = rs[r];
    __syncthreads();
    if (threadIdx.x < 16)
        spart[row0 + threadIdx.x] = wred[threadIdx.x][0] + wred[threadIdx.x][1] +
                                    wred[threadIdx.x][2] + wred[threadIdx.x][3];
}

// ---------- kernel 3: masked softmax over S per batch ----------
__global__ void softmax_kernel(const float* __restrict__ spart, const int* __restrict__ mask,
                               float* __restrict__ wout, int nparts) {
    int b = blockIdx.x, t = threadIdx.x;
    float sc[8]; int mk[8];
    float mx = -1e30f;
#pragma unroll
    for (int i = 0; i < 8; ++i) {
        int s = t + i * 256;
        float vsum = 0.f;
        for (int p = 0; p < nparts; ++p) vsum += spart[(size_t)p * M_TOT + b * S_DIM + s];
        sc[i] = vsum;
        mk[i] = mask[b * S_DIM + s];
        if (mk[i]) mx = fmaxf(mx, vsum);
    }
    for (int o = 1; o < 64; o <<= 1) mx = fmaxf(mx, __shfl_xor(mx, o));
    __shared__ float red[4], red2[4];
    if ((t & 63) == 0) red[t >> 6] = mx;
    __syncthreads();
    mx = fmaxf(fmaxf(red[0], red[1]), fmaxf(red[2], red[3]));
    float sum = 0.f, ev[8];
#pragma unroll
    for (int i = 0; i < 8; ++i) {
        ev[i] = mk[i] ? __expf(sc[i] - mx) : 0.f;
        sum += ev[i];
    }
    for (int o = 1; o < 64; o <<= 1) sum += __shfl_xor(sum, o);
    if ((t & 63) == 0) red2[t >> 6] = sum;
    __syncthreads();
    sum = red2[0] + red2[1] + red2[2] + red2[3];
    float inv = 1.0f / sum;
#pragma unroll
    for (int i = 0; i < 8; ++i) wout[b * S_DIM + t + i * 256] = ev[i] * inv;
}

// ---------- kernel 4: context partial sums (bf16 values, 16B loads) ----------
// grid (32, 32), 128 threads: b, s-chunk of 64; thread t owns d in [t*8, t*8+8)
__global__ void ctx_partial_kernel(const u16* __restrict__ vbf, const float* __restrict__ w,
                                   float* __restrict__ part) {
    int b = blockIdx.x, c = blockIdx.y, t = threadIdx.x;
    const u16* vb = vbf + ((size_t)b * S_DIM + c * 64) * D_DIM + t * 8;
    const float* wb = w + b * S_DIM + c * 64;
    float acc[8];
#pragma unroll
    for (int i = 0; i < 8; ++i) acc[i] = 0.f;
    for (int s = 0; s < 64; ++s) {
        float wv = wb[s];
        u16x8 vv = *(const u16x8*)(vb + (size_t)s * D_DIM);
#pragma unroll
        for (int i = 0; i < 8; ++i) acc[i] += wv * bf2f(vv[i]);
    }
    float* pp = part + ((size_t)b * 32 + c) * D_DIM + t * 8;
#pragma unroll
    for (int i = 0; i < 8; ++i) pp[i] = acc[i];
}
// fp32 variant for fallback path
__global__ void ctx_partial_f32_kernel(const float* __restrict__ values, const float* __restrict__ w,
                                       float* __restrict__ part) {
    int b = blockIdx.x, c = blockIdx.y, t = threadIdx.x;
    const float4* vb = (const float4*)(values + ((size_t)b * S_DIM + c * 256) * D_DIM) + t;
    const float* wb = w + b * S_DIM + c * 256;
    float a0 = 0, a1 = 0, a2 = 0, a3 = 0;
    for (int s = 0; s < 256; ++s) {
        float wv = wb[s];
        float4 vv = vb[(size_t)s * 256];
        a0 += wv * vv.x; a1 += wv * vv.y; a2 += wv * vv.z; a3 += wv * vv.w;
    }
    float* pp = part + ((size_t)b * 8 + c) * D_DIM + t * 4;
    pp[0] = a0; pp[1] = a1; pp[2] = a2; pp[3] = a3;
}

// ---------- kernel 5: reduce context partials ----------
__global__ void ctx_reduce_kernel(const float* __restrict__ part, float* __restrict__ out, int nchunks) {
    int b = blockIdx.x, t = threadIdx.x;
    for (int d = t; d < D_DIM; d += 256) {
        float s = 0.f;
        for (int c = 0; c < nchunks; ++c) s += part[((size_t)b * nchunks + c) * D_DIM + d];
        out[b * D_DIM + d] = s;
    }
}

extern "C" void kernel_launch(void* const* d_in, const int* in_sizes, int n_in,
                              void* d_out, int out_size, void* d_ws, size_t ws_size,
                              hipStream_t stream) {
    const float* query  = (const float*)d_in[0];
    const float* values = (const float*)d_in[1];
    const int*   mask   = (const int*)d_in[2];
    const float* w1     = (const float*)d_in[3];
    const float* b1     = (const float*)d_in[4];
    const float* w2     = (const float*)d_in[5];
    const float* b2     = (const float*)d_in[6];
    const float* v      = (const float*)d_in[7];
    // bv (d_in[8]) shifts all scores equally -> softmax-invariant -> unused.

    float* out  = (float*)d_out;              // context [32][1024]
    float* wout = out + B_DIM * D_DIM;        // attention weights [32][2048]
    char* ws = (char*)d_ws;

    const size_t SZ_VBF = (size_t)M_TOT * D_DIM * 2;    // 134 MB bf16 values
    const size_t SZ_W2T = (size_t)U_DIM * D_DIM * 2;    // 2 MB
    const size_t SZ_QPB = (size_t)B_DIM * U_DIM * 4;    // 128 KB
    const size_t SZ_SPART = (size_t)8 * M_TOT * 4;      // 2 MB (4 used)
    const size_t SZ_PART  = (size_t)B_DIM * 32 * D_DIM * 4; // 4 MB
    const size_t need = SZ_VBF + SZ_W2T + SZ_QPB + SZ_SPART + SZ_PART;

    if (ws_size >= need) {
        u16*   vbf   = (u16*)ws;
        u16*   w2t   = (u16*)(ws + SZ_VBF);
        float* qpb   = (float*)(ws + SZ_VBF + SZ_W2T);
        float* spart = (float*)(ws + SZ_VBF + SZ_W2T + SZ_QPB);
        float* part  = (float*)(ws + SZ_VBF + SZ_W2T + SZ_QPB + SZ_SPART);

        convert_values_kernel<<<2048, 256, 0, stream>>>((const float4*)values, (ushort4*)vbf,
                                                        (long)M_TOT * D_DIM / 4);
        transpose_w2_kernel<<<dim3(32, 32), dim3(32, 8), 0, stream>>>(w2, w2t);
        qproj_kernel<<<dim3(32, 4), 256, 0, stream>>>(query, w1, b1, b2, qpb);
        score_gemm8_kernel<<<1024, 512, 0, stream>>>(vbf, w2t, qpb, v, spart);
        softmax_kernel<<<32, 256, 0, stream>>>(spart, mask, wout, 4);
        ctx_partial_kernel<<<dim3(32, 32), 128, 0, stream>>>(vbf, wout, part);
        ctx_reduce_kernel<<<32, 256, 0, stream>>>(part, out, 32);
    } else {
        // conservative fp32 fallback (no big scratch available)
        float* qpb   = (float*)ws;
        float* spart = (float*)(ws + SZ_QPB);
        float* part  = (float*)(ws + SZ_QPB + (size_t)M_TOT * 4);
        qproj_kernel<<<dim3(32, 4), 256, 0, stream>>>(query, w1, b1, b2, qpb);
        score_fallback_kernel<<<4096, 256, 0, stream>>>(values, w2, qpb, v, spart);
        softmax_kernel<<<32, 256, 0, stream>>>(spart, mask, wout, 1);
        ctx_partial_f32_kernel<<<dim3(32, 8), 256, 0, stream>>>(values, wout, part);
        ctx_reduce_kernel<<<32, 256, 0, stream>>>(part, out, 8);
    }
}

// Round 8
// 329.617 us; speedup vs baseline: 1.3584x; 1.0258x over previous
//
#include <hip/hip_runtime.h>
#include <cstdint>

typedef unsigned short u16;
typedef __bf16 bf16x8 __attribute__((ext_vector_type(8)));
typedef float f32x4 __attribute__((ext_vector_type(4)));
typedef u16 u16x8 __attribute__((ext_vector_type(8)));

#define B_DIM 32
#define S_DIM 2048
#define D_DIM 1024
#define U_DIM 1024
#define M_TOT (B_DIM * S_DIM)   // 65536 rows

// ---------- helpers ----------
__device__ __forceinline__ u16 f2bf(float f) {
    union { float f; uint32_t u; } a; a.f = f;
    uint32_t u = a.u;
    uint32_t r = (u + 0x7FFFu + ((u >> 16) & 1u)) >> 16;   // RNE
    return (u16)r;
}
__device__ __forceinline__ float bf2f(u16 h) {
    union { uint32_t u; float f; } a; a.u = ((uint32_t)h) << 16;
    return a.f;
}
__device__ __forceinline__ float fast_tanh(float x) {
    float ax = fabsf(x);
    float e  = __expf(-2.0f * ax);
    float th = __fdividef(1.0f - e, 1.0f + e);
    return copysignf(th, x);
}
// global -> LDS async copy, 16B per lane
__device__ __forceinline__ void gload_lds16(const void* g, void* l) {
    __builtin_amdgcn_global_load_lds(
        (__attribute__((address_space(1))) void*)(uintptr_t)g,
        (__attribute__((address_space(3))) void*)(uint32_t)(uintptr_t)l,
        16, 0, 0);
}

// ---------- kernel 1a: values f32 -> bf16 ----------
__global__ void convert_values_kernel(const float4* __restrict__ in, ushort4* __restrict__ out, long n4) {
    long i = (long)blockIdx.x * blockDim.x + threadIdx.x;
    long stride = (long)gridDim.x * blockDim.x;
    for (; i < n4; i += stride) {
        float4 v = in[i];
        ushort4 o;
        o.x = f2bf(v.x); o.y = f2bf(v.y); o.z = f2bf(v.z); o.w = f2bf(v.w);
        out[i] = o;
    }
}

// ---------- kernel 1b: w2 [D][U] f32 -> w2t [U][D] bf16 ----------
__global__ void transpose_w2_kernel(const float* __restrict__ w2, u16* __restrict__ w2t) {
    __shared__ float tile[32][33];
    int bx = blockIdx.x * 32, by = blockIdx.y * 32;
    int tx = threadIdx.x, ty = threadIdx.y;  // (32, 8)
    for (int i = 0; i < 32; i += 8)
        tile[ty + i][tx] = w2[(size_t)(by + ty + i) * U_DIM + bx + tx];
    __syncthreads();
    for (int i = 0; i < 32; i += 8)
        w2t[(size_t)(bx + ty + i) * D_DIM + by + tx] = f2bf(tile[tx][ty + i]);
}

// ---------- kernel 1c: qpb[b][u] = query@w1 + b1 + b2 (fp32) ----------
__global__ void qproj_kernel(const float* __restrict__ q, const float* __restrict__ w1,
                             const float* __restrict__ b1, const float* __restrict__ b2,
                             float* __restrict__ qpb) {
    int b = blockIdx.x;
    int u = blockIdx.y * 256 + threadIdx.x;
    __shared__ float ql[D_DIM];
    for (int d = threadIdx.x; d < D_DIM; d += 256) ql[d] = q[b * D_DIM + d];
    __syncthreads();
    float acc = b1[u] + b2[u];
    for (int d = 0; d < D_DIM; ++d) acc += ql[d] * w1[(size_t)d * U_DIM + u];
    qpb[b * U_DIM + u] = acc;
}

// ---------- kernel 2: 256x256-tile, 8-wave, BK=32, ring-4, 1-barrier/tile GEMM ----------
// Ring of 4 LDS slots; stage tile t+3 during tile t (6 phases of load slack);
// single counted vmcnt(8) + single s_barrier per K-tile -> waves drift within a
// tile so DS and MFMA pipes of co-resident waves overlap instead of lockstepping.
__global__ __launch_bounds__(512, 2)
void score_gemm8_kernel(const u16* __restrict__ vbf, const u16* __restrict__ w2t,
                        const float* __restrict__ qpb, const float* __restrict__ vvec,
                        float* __restrict__ spart) {
    const int p    = blockIdx.x;
    const int xcd  = p & 7;
    const int slot = p >> 3;
    const int mt   = xcd * 32 + (slot >> 2);   // 0..255
    const int nt   = slot & 3;                 // 0..3
    const int m0 = mt * 256;
    const int n0 = nt * 256;
    const int b  = m0 >> 11;

    __shared__ __align__(16) __bf16 Abuf[4][256 * 32];   // 64 KB
    __shared__ __align__(16) __bf16 Bbuf[4][256 * 32];   // 64 KB
    __shared__ float qv_lds[256], vv_lds[256];
    __shared__ float red[4][256];

    const int tid  = threadIdx.x;
    const int lane = tid & 63;
    const int wid  = tid >> 6;     // 0..7
    const int wm   = wid >> 2;     // 0..1  (M split)
    const int wn   = wid & 3;      // 0..3  (N split)

    if (tid < 256) qv_lds[tid] = qpb[b * U_DIM + n0 + tid];
    else           vv_lds[tid - 256] = vvec[n0 + (tid - 256)];

    // staging: thread stages rows (tid>>2) and (tid>>2)+128, octet (tid&3),
    // source octet pre-swizzled: oct ^ (r&3) ^ ((r>>2)&3) (same for both rows)
    const int sr = tid >> 2;                                   // 0..127
    const int so = (((tid & 3) ^ (sr & 3) ^ ((sr >> 2) & 3)) << 3);
    const u16* asrc = vbf + (size_t)(m0 + sr) * D_DIM + so;
    const u16* bsrc = w2t + (size_t)(n0 + sr) * D_DIM + so;

    // prologue: stage K-tiles 0,1,2 into slots 0,1,2
    for (int tau = 0; tau < 3; ++tau) {
        const size_t ko = (size_t)tau * 32;
        gload_lds16(asrc + ko,                      &Abuf[tau][tid * 8]);
        gload_lds16(asrc + ko + (size_t)128 * D_DIM, &Abuf[tau][4096 + tid * 8]);
        gload_lds16(bsrc + ko,                      &Bbuf[tau][tid * 8]);
        gload_lds16(bsrc + ko + (size_t)128 * D_DIM, &Bbuf[tau][4096 + tid * 8]);
    }

    f32x4 acc[8][4];
#pragma unroll
    for (int mi = 0; mi < 8; ++mi)
#pragma unroll
        for (int nj = 0; nj < 4; ++nj) acc[mi][nj] = (f32x4){0.f, 0.f, 0.f, 0.f};

    const int colL = lane & 15;
    const int grp  = lane >> 4;
    // read-side swizzled k-octet (constant per lane for all fragments)
    const int kswz = ((grp ^ (colL & 3) ^ ((colL >> 2) & 3)) << 3);
    const int arow = wm * 128 + colL;
    const int brow = wn * 64 + colL;

    auto compute_tile = [&](const __bf16* Ac, const __bf16* Bc) {
        bf16x8 aR[4], bR[4];
#pragma unroll
        for (int mi = 0; mi < 4; ++mi) aR[mi] = *(const bf16x8*)&Ac[(arow + mi * 16) * 32 + kswz];
#pragma unroll
        for (int nj = 0; nj < 4; ++nj) bR[nj] = *(const bf16x8*)&Bc[(brow + nj * 16) * 32 + kswz];
        __builtin_amdgcn_s_setprio(1);
#pragma unroll
        for (int mi = 0; mi < 4; ++mi)
#pragma unroll
            for (int nj = 0; nj < 4; ++nj)
                acc[mi][nj] = __builtin_amdgcn_mfma_f32_16x16x32_bf16(aR[mi], bR[nj], acc[mi][nj], 0, 0, 0);
        __builtin_amdgcn_s_setprio(0);
#pragma unroll
        for (int mi = 0; mi < 4; ++mi) aR[mi] = *(const bf16x8*)&Ac[(arow + 64 + mi * 16) * 32 + kswz];
        __builtin_amdgcn_s_setprio(1);
#pragma unroll
        for (int mi = 0; mi < 4; ++mi)
#pragma unroll
            for (int nj = 0; nj < 4; ++nj)
                acc[mi + 4][nj] = __builtin_amdgcn_mfma_f32_16x16x32_bf16(aR[mi], bR[nj], acc[mi + 4][nj], 0, 0, 0);
        __builtin_amdgcn_s_setprio(0);
    };

    // main loop: tiles 0..29 (staging for t+3 while t+3 <= 31)
    for (int t = 0; t < 30; ++t) {
        __builtin_amdgcn_sched_barrier(0);              // pin prev tile's lgkm waits above
        asm volatile("s_waitcnt vmcnt(8)" ::: "memory"); // own tile-t loads drained
        __builtin_amdgcn_s_barrier();
        __builtin_amdgcn_sched_barrier(0);
        if (t < 29) {
            const int st = (t + 3) & 3;
            const size_t ko = (size_t)(t + 3) * 32;
            gload_lds16(asrc + ko,                       &Abuf[st][tid * 8]);
            gload_lds16(asrc + ko + (size_t)128 * D_DIM, &Abuf[st][4096 + tid * 8]);
            gload_lds16(bsrc + ko,                       &Bbuf[st][tid * 8]);
            gload_lds16(bsrc + ko + (size_t)128 * D_DIM, &Bbuf[st][4096 + tid * 8]);
        }
        __builtin_amdgcn_sched_barrier(0);
        compute_tile(&Abuf[t & 3][0], &Bbuf[t & 3][0]);
    }
    // tile 30
    __builtin_amdgcn_sched_barrier(0);
    asm volatile("s_waitcnt vmcnt(4)" ::: "memory");
    __builtin_amdgcn_s_barrier();
    compute_tile(&Abuf[30 & 3][0], &Bbuf[30 & 3][0]);
    // tile 31
    __builtin_amdgcn_sched_barrier(0);
    asm volatile("s_waitcnt vmcnt(0)" ::: "memory");
    __builtin_amdgcn_s_barrier();
    compute_tile(&Abuf[31 & 3][0], &Bbuf[31 & 3][0]);

    // ---- fused epilogue: tanh(x + qpb)*v, reduce over this block's 256 cols ----
    float rs[8][4];
#pragma unroll
    for (int mi = 0; mi < 8; ++mi)
#pragma unroll
        for (int r = 0; r < 4; ++r) rs[mi][r] = 0.f;

#pragma unroll
    for (int nj = 0; nj < 4; ++nj) {
        const int cl = wn * 64 + nj * 16 + colL;
        const float qadd = qv_lds[cl];
        const float vmul = vv_lds[cl];
#pragma unroll
        for (int mi = 0; mi < 8; ++mi)
#pragma unroll
            for (int r = 0; r < 4; ++r)
                rs[mi][r] += fast_tanh(acc[mi][nj][r] + qadd) * vmul;
    }
#pragma unroll
    for (int mi = 0; mi < 8; ++mi)
#pragma unroll
        for (int r = 0; r < 4; ++r) {
            float s = rs[mi][r];
            s += __shfl_xor(s, 1); s += __shfl_xor(s, 2);
            s += __shfl_xor(s, 4); s += __shfl_xor(s, 8);
            if (colL == 0) red[wn][wm * 128 + mi * 16 + grp * 4 + r] = s;
        }
    __syncthreads();
    if (tid < 256)
        spart[(size_t)nt * M_TOT + m0 + tid] =
            red[0][tid] + red[1][tid] + red[2][tid] + red[3][tid];
}

// ---------- fallback score kernel (fp32, no MFMA) ----------
__global__ __launch_bounds__(256)
void score_fallback_kernel(const float* __restrict__ values, const float* __restrict__ w2,
                           const float* __restrict__ qpb, const float* __restrict__ vvec,
                           float* __restrict__ spart) {
    int row0 = blockIdx.x * 16;
    int b = row0 >> 11;
    __shared__ float vr[16][D_DIM];
    for (int i = threadIdx.x; i < 16 * D_DIM; i += 256)
        vr[i >> 10][i & 1023] = values[(size_t)row0 * D_DIM + i];
    __syncthreads();
    float rs[16];
#pragma unroll
    for (int r = 0; r < 16; ++r) rs[r] = 0.f;
    for (int uu = threadIdx.x; uu < U_DIM; uu += 256) {
        float acc[16];
#pragma unroll
        for (int r = 0; r < 16; ++r) acc[r] = 0.f;
        for (int d = 0; d < D_DIM; ++d) {
            float wv = w2[(size_t)d * U_DIM + uu];
#pragma unroll
            for (int r = 0; r < 16; ++r) acc[r] += vr[r][d] * wv;
        }
        float qv = qpb[b * U_DIM + uu], vu = vvec[uu];
#pragma unroll
        for (int r = 0; r < 16; ++r) rs[r] += fast_tanh(acc[r] + qv) * vu;
    }
#pragma unroll
    for (int r = 0; r < 16; ++r) {
        float s = rs[r];
        for (int o = 1; o < 64; o <<= 1) s += __shfl_xor(s, o);
        rs[r] = s;
    }
    __shared__ float wred[16][4];
    int lane = threadIdx.x & 63, wid = threadIdx.x >> 6;
    if (lane == 0)
        for (int r = 0; r < 16; ++r) wred[r][wid] = rs[r];
    __syncthreads();
    if (threadIdx.x < 16)
        spart[row0 + threadIdx.x] = wred[threadIdx.x][0] + wred[threadIdx.x][1] +
                                    wred[threadIdx.x][2] + wred[threadIdx.x][3];
}

// ---------- kernel 3: masked softmax over S per batch ----------
__global__ void softmax_kernel(const float* __restrict__ spart, const int* __restrict__ mask,
                               float* __restrict__ wout, int nparts) {
    int b = blockIdx.x, t = threadIdx.x;
    float sc[8]; int mk[8];
    float mx = -1e30f;
#pragma unroll
    for (int i = 0; i < 8; ++i) {
        int s = t + i * 256;
        float vsum = 0.f;
        for (int p = 0; p < nparts; ++p) vsum += spart[(size_t)p * M_TOT + b * S_DIM + s];
        sc[i] = vsum;
        mk[i] = mask[b * S_DIM + s];
        if (mk[i]) mx = fmaxf(mx, vsum);
    }
    for (int o = 1; o < 64; o <<= 1) mx = fmaxf(mx, __shfl_xor(mx, o));
    __shared__ float red[4], red2[4];
    if ((t & 63) == 0) red[t >> 6] = mx;
    __syncthreads();
    mx = fmaxf(fmaxf(red[0], red[1]), fmaxf(red[2], red[3]));
    float sum = 0.f, ev[8];
#pragma unroll
    for (int i = 0; i < 8; ++i) {
        ev[i] = mk[i] ? __expf(sc[i] - mx) : 0.f;
        sum += ev[i];
    }
    for (int o = 1; o < 64; o <<= 1) sum += __shfl_xor(sum, o);
    if ((t & 63) == 0) red2[t >> 6] = sum;
    __syncthreads();
    sum = red2[0] + red2[1] + red2[2] + red2[3];
    float inv = 1.0f / sum;
#pragma unroll
    for (int i = 0; i < 8; ++i) wout[b * S_DIM + t + i * 256] = ev[i] * inv;
}

// ---------- kernel 4: context partial sums (bf16 values, 16B loads) ----------
// grid (32, 16), 128 threads: b, s-chunk of 128; thread t owns d in [t*8, t*8+8)
__global__ void ctx_partial_kernel(const u16* __restrict__ vbf, const float* __restrict__ w,
                                   float* __restrict__ part) {
    int b = blockIdx.x, c = blockIdx.y, t = threadIdx.x;
    const u16* vb = vbf + ((size_t)b * S_DIM + c * 128) * D_DIM + t * 8;
    const float* wb = w + b * S_DIM + c * 128;
    float acc[8];
#pragma unroll
    for (int i = 0; i < 8; ++i) acc[i] = 0.f;
    for (int s = 0; s < 128; ++s) {
        float wv = wb[s];
        u16x8 vv = *(const u16x8*)(vb + (size_t)s * D_DIM);
#pragma unroll
        for (int i = 0; i < 8; ++i) acc[i] += wv * bf2f(vv[i]);
    }
    float* pp = part + ((size_t)b * 16 + c) * D_DIM + t * 8;
#pragma unroll
    for (int i = 0; i < 8; ++i) pp[i] = acc[i];
}
// fp32 variant for fallback path
__global__ void ctx_partial_f32_kernel(const float* __restrict__ values, const float* __restrict__ w,
                                       float* __restrict__ part) {
    int b = blockIdx.x, c = blockIdx.y, t = threadIdx.x;
    const float4* vb = (const float4*)(values + ((size_t)b * S_DIM + c * 256) * D_DIM) + t;
    const float* wb = w + b * S_DIM + c * 256;
    float a0 = 0, a1 = 0, a2 = 0, a3 = 0;
    for (int s = 0; s < 256; ++s) {
        float wv = wb[s];
        float4 vv = vb[(size_t)s * 256];
        a0 += wv * vv.x; a1 += wv * vv.y; a2 += wv * vv.z; a3 += wv * vv.w;
    }
    float* pp = part + ((size_t)b * 8 + c) * D_DIM + t * 4;
    pp[0] = a0; pp[1] = a1; pp[2] = a2; pp[3] = a3;
}

// ---------- kernel 5: reduce context partials ----------
__global__ void ctx_reduce_kernel(const float* __restrict__ part, float* __restrict__ out, int nchunks) {
    int b = blockIdx.x, t = threadIdx.x;
    for (int d = t; d < D_DIM; d += 256) {
        float s = 0.f;
        for (int c = 0; c < nchunks; ++c) s += part[((size_t)b * nchunks + c) * D_DIM + d];
        out[b * D_DIM + d] = s;
    }
}

extern "C" void kernel_launch(void* const* d_in, const int* in_sizes, int n_in,
                              void* d_out, int out_size, void* d_ws, size_t ws_size,
                              hipStream_t stream) {
    const float* query  = (const float*)d_in[0];
    const float* values = (const float*)d_in[1];
    const int*   mask   = (const int*)d_in[2];
    const float* w1     = (const float*)d_in[3];
    const float* b1     = (const float*)d_in[4];
    const float* w2     = (const float*)d_in[5];
    const float* b2     = (const float*)d_in[6];
    const float* v      = (const float*)d_in[7];
    // bv (d_in[8]) shifts all scores equally -> softmax-invariant -> unused.

    float* out  = (float*)d_out;              // context [32][1024]
    float* wout = out + B_DIM * D_DIM;        // attention weights [32][2048]
    char* ws = (char*)d_ws;

    const size_t SZ_VBF = (size_t)M_TOT * D_DIM * 2;    // 134 MB bf16 values
    const size_t SZ_W2T = (size_t)U_DIM * D_DIM * 2;    // 2 MB
    const size_t SZ_QPB = (size_t)B_DIM * U_DIM * 4;    // 128 KB
    const size_t SZ_SPART = (size_t)8 * M_TOT * 4;      // 2 MB (4 used)
    const size_t SZ_PART  = (size_t)B_DIM * 16 * D_DIM * 4; // 2 MB
    const size_t need = SZ_VBF + SZ_W2T + SZ_QPB + SZ_SPART + SZ_PART;

    if (ws_size >= need) {
        u16*   vbf   = (u16*)ws;
        u16*   w2t   = (u16*)(ws + SZ_VBF);
        float* qpb   = (float*)(ws + SZ_VBF + SZ_W2T);
        float* spart = (float*)(ws + SZ_VBF + SZ_W2T + SZ_QPB);
        float* part  = (float*)(ws + SZ_VBF + SZ_W2T + SZ_QPB + SZ_SPART);

        convert_values_kernel<<<2048, 256, 0, stream>>>((const float4*)values, (ushort4*)vbf,
                                                        (long)M_TOT * D_DIM / 4);
        transpose_w2_kernel<<<dim3(32, 32), dim3(32, 8), 0, stream>>>(w2, w2t);
        qproj_kernel<<<dim3(32, 4), 256, 0, stream>>>(query, w1, b1, b2, qpb);
        score_gemm8_kernel<<<1024, 512, 0, stream>>>(vbf, w2t, qpb, v, spart);
        softmax_kernel<<<32, 256, 0, stream>>>(spart, mask, wout, 4);
        ctx_partial_kernel<<<dim3(32, 16), 128, 0, stream>>>(vbf, wout, part);
        ctx_reduce_kernel<<<32, 256, 0, stream>>>(part, out, 16);
    } else {
        // conservative fp32 fallback (no big scratch available)
        float* qpb   = (float*)ws;
        float* spart = (float*)(ws + SZ_QPB);
        float* part  = (float*)(ws + SZ_QPB + (size_t)M_TOT * 4);
        qproj_kernel<<<dim3(32, 4), 256, 0, stream>>>(query, w1, b1, b2, qpb);
        score_fallback_kernel<<<4096, 256, 0, stream>>>(values, w2, qpb, v, spart);
        softmax_kernel<<<32, 256, 0, stream>>>(spart, mask, wout, 1);
        ctx_partial_f32_kernel<<<dim3(32, 8), 256, 0, stream>>>(values, wout, part);
        ctx_reduce_kernel<<<32, 256, 0, stream>>>(part, out, 8);
    }
}

// Round 9
// 316.780 us; speedup vs baseline: 1.4135x; 1.0405x over previous
//
#include <hip/hip_runtime.h>
#include <cstdint>

typedef unsigned short u16;
typedef __bf16 bf16x8 __attribute__((ext_vector_type(8)));
typedef float f32x4 __attribute__((ext_vector_type(4)));
typedef u16 u16x8 __attribute__((ext_vector_type(8)));

#define B_DIM 32
#define S_DIM 2048
#define D_DIM 1024
#define U_DIM 1024
#define M_TOT (B_DIM * S_DIM)   // 65536 rows

// ---------- helpers ----------
__device__ __forceinline__ u16 f2bf(float f) {
    union { float f; uint32_t u; } a; a.f = f;
    uint32_t u = a.u;
    uint32_t r = (u + 0x7FFFu + ((u >> 16) & 1u)) >> 16;   // RNE
    return (u16)r;
}
__device__ __forceinline__ float bf2f(u16 h) {
    union { uint32_t u; float f; } a; a.u = ((uint32_t)h) << 16;
    return a.f;
}
__device__ __forceinline__ float fast_tanh(float x) {
    float ax = fabsf(x);
    float e  = __expf(-2.0f * ax);
    float th = __fdividef(1.0f - e, 1.0f + e);
    return copysignf(th, x);
}
// global -> LDS async copy, 16B per lane
__device__ __forceinline__ void gload_lds16(const void* g, void* l) {
    __builtin_amdgcn_global_load_lds(
        (__attribute__((address_space(1))) void*)(uintptr_t)g,
        (__attribute__((address_space(3))) void*)(uint32_t)(uintptr_t)l,
        16, 0, 0);
}

// ---------- kernel 1a: values f32 -> bf16 ----------
__global__ void convert_values_kernel(const float4* __restrict__ in, ushort4* __restrict__ out, long n4) {
    long i = (long)blockIdx.x * blockDim.x + threadIdx.x;
    long stride = (long)gridDim.x * blockDim.x;
    for (; i < n4; i += stride) {
        float4 v = in[i];
        ushort4 o;
        o.x = f2bf(v.x); o.y = f2bf(v.y); o.z = f2bf(v.z); o.w = f2bf(v.w);
        out[i] = o;
    }
}

// ---------- kernel 1b: w2 [D][U] f32 -> w2t [U][D] bf16 ----------
__global__ void transpose_w2_kernel(const float* __restrict__ w2, u16* __restrict__ w2t) {
    __shared__ float tile[32][33];
    int bx = blockIdx.x * 32, by = blockIdx.y * 32;
    int tx = threadIdx.x, ty = threadIdx.y;  // (32, 8)
    for (int i = 0; i < 32; i += 8)
        tile[ty + i][tx] = w2[(size_t)(by + ty + i) * U_DIM + bx + tx];
    __syncthreads();
    for (int i = 0; i < 32; i += 8)
        w2t[(size_t)(bx + ty + i) * D_DIM + by + tx] = f2bf(tile[tx][ty + i]);
}

// ---------- kernel 1c: qpb[b][u] = query@w1 + b1 + b2 (fp32) ----------
__global__ void qproj_kernel(const float* __restrict__ q, const float* __restrict__ w1,
                             const float* __restrict__ b1, const float* __restrict__ b2,
                             float* __restrict__ qpb) {
    int b = blockIdx.x;
    int u = blockIdx.y * 256 + threadIdx.x;
    __shared__ float ql[D_DIM];
    for (int d = threadIdx.x; d < D_DIM; d += 256) ql[d] = q[b * D_DIM + d];
    __syncthreads();
    float acc = b1[u] + b2[u];
    for (int d = 0; d < D_DIM; ++d) acc += ql[d] * w1[(size_t)d * U_DIM + u];
    qpb[b * U_DIM + u] = acc;
}

// ---------- kernel 2: 256x256-tile, 8-wave, 4-phase/K-tile, counted-vmcnt GEMM ----------
// Round-3 skeleton; ONE change: P1-P3 issue their ds_reads + stage pair BEFORE the
// phase barrier (reads fly under the barrier wait / other waves' MFMA), lgkm drain
// happens at the MFMA head. Breaks the all-read-then-all-MFMA pipe serialization.
__global__ __launch_bounds__(512, 2)
void score_gemm8_kernel(const u16* __restrict__ vbf, const u16* __restrict__ w2t,
                        const float* __restrict__ qpb, const float* __restrict__ vvec,
                        float* __restrict__ spart) {
    const int p    = blockIdx.x;
    const int xcd  = p & 7;
    const int slot = p >> 3;
    const int mt   = xcd * 32 + (slot >> 2);   // 0..255
    const int nt   = slot & 3;                 // 0..3
    const int m0 = mt * 256;
    const int n0 = nt * 256;
    const int b  = m0 >> 11;

    __shared__ __align__(16) __bf16 Abuf[2][256 * 64];   // 64 KB
    __shared__ __align__(16) __bf16 Bbuf[2][256 * 64];   // 64 KB
    __shared__ float qv_lds[256], vv_lds[256];
    __shared__ float red[4][256];

    const int tid  = threadIdx.x;
    const int lane = tid & 63;
    const int wid  = tid >> 6;     // 0..7
    const int wm   = wid >> 2;     // 0..1  (M split)
    const int wn   = wid & 3;      // 0..3  (N split)

    if (tid < 256) qv_lds[tid] = qpb[b * U_DIM + n0 + tid];
    else           vv_lds[tid - 256] = vvec[n0 + (tid - 256)];

    // staging: thread t -> LDS linear bytes [t*16, t*16+16) (+ j*4096 per issue)
    // source column pre-swizzled so that LDS holds the XOR-swizzled layout
    const int tr = tid >> 3;                              // 0..63 (row within issue)
    const int sc = (((tid & 7) ^ (tr & 7)) << 3);         // swizzled source col (elems)
    const u16* asrc = vbf + (size_t)(m0 + tr) * D_DIM + sc;
    const u16* bsrc = w2t + (size_t)(n0 + tr) * D_DIM + sc;

    // prologue: stage K-tile 0 into buffer 0
#pragma unroll
    for (int j = 0; j < 4; ++j) {
        gload_lds16(asrc + (size_t)j * 64 * D_DIM, &Abuf[0][j * 4096 + tid * 8]);
        gload_lds16(bsrc + (size_t)j * 64 * D_DIM, &Bbuf[0][j * 4096 + tid * 8]);
    }

    f32x4 acc[8][4];
#pragma unroll
    for (int mi = 0; mi < 8; ++mi)
#pragma unroll
        for (int nj = 0; nj < 4; ++nj) acc[mi][nj] = (f32x4){0.f, 0.f, 0.f, 0.f};

    const int colL = lane & 15;
    const int grp  = lane >> 4;
    const int xork = (lane & 7) << 3;
    const int kix0 = (grp * 8) ^ xork;        // kk=0 swizzled col
    const int kix1 = ((32 + grp * 8)) ^ xork; // kk=1 swizzled col
    const int arow = wm * 128 + colL;
    const int brow = wn * 64 + colL;

    bf16x8 aR[4], bR[4];

    for (int t = 0; t < 16; ++t) {
        const int cur = t & 1, nxt = cur ^ 1;
        const __bf16* Ac = Abuf[cur];
        const __bf16* Bc = Bbuf[cur];
        const size_t kofs = (size_t)(t + 1) * 64;

        // ---- publish tile t ----
        if (t < 15) {
            gload_lds16(asrc + kofs,                   &Abuf[nxt][tid * 8]);
            gload_lds16(asrc + kofs + (size_t)65536,   &Abuf[nxt][4096 + tid * 8]);
            asm volatile("s_waitcnt vmcnt(2)" ::: "memory");  // tile t's 8 loads landed
        } else {
            asm volatile("s_waitcnt vmcnt(0)" ::: "memory");
        }
        __builtin_amdgcn_s_barrier();
        __builtin_amdgcn_sched_barrier(0);

        // ================= P0: reads (kk0, A mi0-3 + B) then MFMA =================
#pragma unroll
        for (int mi = 0; mi < 4; ++mi) aR[mi] = *(const bf16x8*)&Ac[(arow + mi * 16) * 64 + kix0];
#pragma unroll
        for (int nj = 0; nj < 4; ++nj) bR[nj] = *(const bf16x8*)&Bc[(brow + nj * 16) * 64 + kix0];
        __builtin_amdgcn_s_setprio(1);
#pragma unroll
        for (int mi = 0; mi < 4; ++mi)
#pragma unroll
            for (int nj = 0; nj < 4; ++nj)
                acc[mi][nj] = __builtin_amdgcn_mfma_f32_16x16x32_bf16(aR[mi], bR[nj], acc[mi][nj], 0, 0, 0);
        __builtin_amdgcn_s_setprio(0);

        // ================= P1: pre-issue reads (A mi4-7 kk0) + stage A23; barrier; MFMA ===
#pragma unroll
        for (int mi = 0; mi < 4; ++mi) aR[mi] = *(const bf16x8*)&Ac[(arow + 64 + mi * 16) * 64 + kix0];
        if (t < 15) {
            gload_lds16(asrc + kofs + (size_t)2 * 65536, &Abuf[nxt][2 * 4096 + tid * 8]);
            gload_lds16(asrc + kofs + (size_t)3 * 65536, &Abuf[nxt][3 * 4096 + tid * 8]);
        }
        __builtin_amdgcn_sched_barrier(0);
        __builtin_amdgcn_s_barrier();
        __builtin_amdgcn_s_setprio(1);
#pragma unroll
        for (int mi = 0; mi < 4; ++mi)
#pragma unroll
            for (int nj = 0; nj < 4; ++nj)
                acc[mi + 4][nj] = __builtin_amdgcn_mfma_f32_16x16x32_bf16(aR[mi], bR[nj], acc[mi + 4][nj], 0, 0, 0);
        __builtin_amdgcn_s_setprio(0);

        // ================= P2: pre-issue reads (kk1, A mi0-3 + B) + stage B01; barrier; MFMA
#pragma unroll
        for (int mi = 0; mi < 4; ++mi) aR[mi] = *(const bf16x8*)&Ac[(arow + mi * 16) * 64 + kix1];
#pragma unroll
        for (int nj = 0; nj < 4; ++nj) bR[nj] = *(const bf16x8*)&Bc[(brow + nj * 16) * 64 + kix1];
        if (t < 15) {
            gload_lds16(bsrc + kofs,                   &Bbuf[nxt][tid * 8]);
            gload_lds16(bsrc + kofs + (size_t)65536,   &Bbuf[nxt][4096 + tid * 8]);
        }
        __builtin_amdgcn_sched_barrier(0);
        __builtin_amdgcn_s_barrier();
        __builtin_amdgcn_s_setprio(1);
#pragma unroll
        for (int mi = 0; mi < 4; ++mi)
#pragma unroll
            for (int nj = 0; nj < 4; ++nj)
                acc[mi][nj] = __builtin_amdgcn_mfma_f32_16x16x32_bf16(aR[mi], bR[nj], acc[mi][nj], 0, 0, 0);
        __builtin_amdgcn_s_setprio(0);

        // ================= P3: pre-issue reads (A mi4-7 kk1) + stage B23; barrier; MFMA ===
#pragma unroll
        for (int mi = 0; mi < 4; ++mi) aR[mi] = *(const bf16x8*)&Ac[(arow + 64 + mi * 16) * 64 + kix1];
        if (t < 15) {
            gload_lds16(bsrc + kofs + (size_t)2 * 65536, &Bbuf[nxt][2 * 4096 + tid * 8]);
            gload_lds16(bsrc + kofs + (size_t)3 * 65536, &Bbuf[nxt][3 * 4096 + tid * 8]);
        }
        __builtin_amdgcn_sched_barrier(0);
        __builtin_amdgcn_s_barrier();
        __builtin_amdgcn_s_setprio(1);
#pragma unroll
        for (int mi = 0; mi < 4; ++mi)
#pragma unroll
            for (int nj = 0; nj < 4; ++nj)
                acc[mi + 4][nj] = __builtin_amdgcn_mfma_f32_16x16x32_bf16(aR[mi], bR[nj], acc[mi + 4][nj], 0, 0, 0);
        __builtin_amdgcn_s_setprio(0);
        // loop-top pub barrier closes the tile
    }

    // ---- fused epilogue: tanh(x + qpb)*v, reduce over this block's 256 cols ----
    float rs[8][4];
#pragma unroll
    for (int mi = 0; mi < 8; ++mi)
#pragma unroll
        for (int r = 0; r < 4; ++r) rs[mi][r] = 0.f;

#pragma unroll
    for (int nj = 0; nj < 4; ++nj) {
        const int cl = wn * 64 + nj * 16 + colL;
        const float qadd = qv_lds[cl];
        const float vmul = vv_lds[cl];
#pragma unroll
        for (int mi = 0; mi < 8; ++mi)
#pragma unroll
            for (int r = 0; r < 4; ++r)
                rs[mi][r] += fast_tanh(acc[mi][nj][r] + qadd) * vmul;
    }
#pragma unroll
    for (int mi = 0; mi < 8; ++mi)
#pragma unroll
        for (int r = 0; r < 4; ++r) {
            float s = rs[mi][r];
            s += __shfl_xor(s, 1); s += __shfl_xor(s, 2);
            s += __shfl_xor(s, 4); s += __shfl_xor(s, 8);
            if (colL == 0) red[wn][wm * 128 + mi * 16 + grp * 4 + r] = s;
        }
    __syncthreads();
    if (tid < 256)
        spart[(size_t)nt * M_TOT + m0 + tid] =
            red[0][tid] + red[1][tid] + red[2][tid] + red[3][tid];
}

// ---------- fallback score kernel (fp32, no MFMA) ----------
__global__ __launch_bounds__(256)
void score_fallback_kernel(const float* __restrict__ values, const float* __restrict__ w2,
                           const float* __restrict__ qpb, const float* __restrict__ vvec,
                           float* __restrict__ spart) {
    int row0 = blockIdx.x * 16;
    int b = row0 >> 11;
    __shared__ float vr[16][D_DIM];
    for (int i = threadIdx.x; i < 16 * D_DIM; i += 256)
        vr[i >> 10][i & 1023] = values[(size_t)row0 * D_DIM + i];
    __syncthreads();
    float rs[16];
#pragma unroll
    for (int r = 0; r < 16; ++r) rs[r] = 0.f;
    for (int uu = threadIdx.x; uu < U_DIM; uu += 256) {
        float acc[16];
#pragma unroll
        for (int r = 0; r < 16; ++r) acc[r] = 0.f;
        for (int d = 0; d < D_DIM; ++d) {
            float wv = w2[(size_t)d * U_DIM + uu];
#pragma unroll
            for (int r = 0; r < 16; ++r) acc[r] += vr[r][d] * wv;
        }
        float qv = qpb[b * U_DIM + uu], vu = vvec[uu];
#pragma unroll
        for (int r = 0; r < 16; ++r) rs[r] += fast_tanh(acc[r] + qv) * vu;
    }
#pragma unroll
    for (int r = 0; r < 16; ++r) {
        float s = rs[r];
        for (int o = 1; o < 64; o <<= 1) s += __shfl_xor(s, o);
        rs[r] = s;
    }
    __shared__ float wred[16][4];
    int lane = threadIdx.x & 63, wid = threadIdx.x >> 6;
    if (lane == 0)
        for (int r = 0; r < 16; ++r) wred[r][wid] = rs[r];
    __syncthreads();
    if (threadIdx.x < 16)
        spart[row0 + threadIdx.x] = wred[threadIdx.x][0] + wred[threadIdx.x][1] +
                                    wred[threadIdx.x][2] + wred[threadIdx.x][3];
}

// ---------- kernel 3: masked softmax over S per batch ----------
__global__ void softmax_kernel(const float* __restrict__ spart, const int* __restrict__ mask,
                               float* __restrict__ wout, int nparts) {
    int b = blockIdx.x, t = threadIdx.x;
    float sc[8]; int mk[8];
    float mx = -1e30f;
#pragma unroll
    for (int i = 0; i < 8; ++i) {
        int s = t + i * 256;
        float vsum = 0.f;
        for (int p = 0; p < nparts; ++p) vsum += spart[(size_t)p * M_TOT + b * S_DIM + s];
        sc[i] = vsum;
        mk[i] = mask[b * S_DIM + s];
        if (mk[i]) mx = fmaxf(mx, vsum);
    }
    for (int o = 1; o < 64; o <<= 1) mx = fmaxf(mx, __shfl_xor(mx, o));
    __shared__ float red[4], red2[4];
    if ((t & 63) == 0) red[t >> 6] = mx;
    __syncthreads();
    mx = fmaxf(fmaxf(red[0], red[1]), fmaxf(red[2], red[3]));
    float sum = 0.f, ev[8];
#pragma unroll
    for (int i = 0; i < 8; ++i) {
        ev[i] = mk[i] ? __expf(sc[i] - mx) : 0.f;
        sum += ev[i];
    }
    for (int o = 1; o < 64; o <<= 1) sum += __shfl_xor(sum, o);
    if ((t & 63) == 0) red2[t >> 6] = sum;
    __syncthreads();
    sum = red2[0] + red2[1] + red2[2] + red2[3];
    float inv = 1.0f / sum;
#pragma unroll
    for (int i = 0; i < 8; ++i) wout[b * S_DIM + t + i * 256] = ev[i] * inv;
}

// ---------- kernel 4: context partial sums (bf16 values, 16B loads) ----------
// grid (32, 16), 128 threads: b, s-chunk of 128; thread t owns d in [t*8, t*8+8)
__global__ void ctx_partial_kernel(const u16* __restrict__ vbf, const float* __restrict__ w,
                                   float* __restrict__ part) {
    int b = blockIdx.x, c = blockIdx.y, t = threadIdx.x;
    const u16* vb = vbf + ((size_t)b * S_DIM + c * 128) * D_DIM + t * 8;
    const float* wb = w + b * S_DIM + c * 128;
    float acc[8];
#pragma unroll
    for (int i = 0; i < 8; ++i) acc[i] = 0.f;
    for (int s = 0; s < 128; ++s) {
        float wv = wb[s];
        u16x8 vv = *(const u16x8*)(vb + (size_t)s * D_DIM);
#pragma unroll
        for (int i = 0; i < 8; ++i) acc[i] += wv * bf2f(vv[i]);
    }
    float* pp = part + ((size_t)b * 16 + c) * D_DIM + t * 8;
#pragma unroll
    for (int i = 0; i < 8; ++i) pp[i] = acc[i];
}
// fp32 variant for fallback path
__global__ void ctx_partial_f32_kernel(const float* __restrict__ values, const float* __restrict__ w,
                                       float* __restrict__ part) {
    int b = blockIdx.x, c = blockIdx.y, t = threadIdx.x;
    const float4* vb = (const float4*)(values + ((size_t)b * S_DIM + c * 256) * D_DIM) + t;
    const float* wb = w + b * S_DIM + c * 256;
    float a0 = 0, a1 = 0, a2 = 0, a3 = 0;
    for (int s = 0; s < 256; ++s) {
        float wv = wb[s];
        float4 vv = vb[(size_t)s * 256];
        a0 += wv * vv.x; a1 += wv * vv.y; a2 += wv * vv.z; a3 += wv * vv.w;
    }
    float* pp = part + ((size_t)b * 8 + c) * D_DIM + t * 4;
    pp[0] = a0; pp[1] = a1; pp[2] = a2; pp[3] = a3;
}

// ---------- kernel 5: reduce context partials ----------
__global__ void ctx_reduce_kernel(const float* __restrict__ part, float* __restrict__ out, int nchunks) {
    int b = blockIdx.x, t = threadIdx.x;
    for (int d = t; d < D_DIM; d += 256) {
        float s = 0.f;
        for (int c = 0; c < nchunks; ++c) s += part[((size_t)b * nchunks + c) * D_DIM + d];
        out[b * D_DIM + d] = s;
    }
}

extern "C" void kernel_launch(void* const* d_in, const int* in_sizes, int n_in,
                              void* d_out, int out_size, void* d_ws, size_t ws_size,
                              hipStream_t stream) {
    const float* query  = (const float*)d_in[0];
    const float* values = (const float*)d_in[1];
    const int*   mask   = (const int*)d_in[2];
    const float* w1     = (const float*)d_in[3];
    const float* b1     = (const float*)d_in[4];
    const float* w2     = (const float*)d_in[5];
    const float* b2     = (const float*)d_in[6];
    const float* v      = (const float*)d_in[7];
    // bv (d_in[8]) shifts all scores equally -> softmax-invariant -> unused.

    float* out  = (float*)d_out;              // context [32][1024]
    float* wout = out + B_DIM * D_DIM;        // attention weights [32][2048]
    char* ws = (char*)d_ws;

    const size_t SZ_VBF = (size_t)M_TOT * D_DIM * 2;    // 134 MB bf16 values
    const size_t SZ_W2T = (size_t)U_DIM * D_DIM * 2;    // 2 MB
    const size_t SZ_QPB = (size_t)B_DIM * U_DIM * 4;    // 128 KB
    const size_t SZ_SPART = (size_t)8 * M_TOT * 4;      // 2 MB (4 used)
    const size_t SZ_PART  = (size_t)B_DIM * 16 * D_DIM * 4; // 2 MB
    const size_t need = SZ_VBF + SZ_W2T + SZ_QPB + SZ_SPART + SZ_PART;

    if (ws_size >= need) {
        u16*   vbf   = (u16*)ws;
        u16*   w2t   = (u16*)(ws + SZ_VBF);
        float* qpb   = (float*)(ws + SZ_VBF + SZ_W2T);
        float* spart = (float*)(ws + SZ_VBF + SZ_W2T + SZ_QPB);
        float* part  = (float*)(ws + SZ_VBF + SZ_W2T + SZ_QPB + SZ_SPART);

        convert_values_kernel<<<2048, 256, 0, stream>>>((const float4*)values, (ushort4*)vbf,
                                                        (long)M_TOT * D_DIM / 4);
        transpose_w2_kernel<<<dim3(32, 32), dim3(32, 8), 0, stream>>>(w2, w2t);
        qproj_kernel<<<dim3(32, 4), 256, 0, stream>>>(query, w1, b1, b2, qpb);
        score_gemm8_kernel<<<1024, 512, 0, stream>>>(vbf, w2t, qpb, v, spart);
        softmax_kernel<<<32, 256, 0, stream>>>(spart, mask, wout, 4);
        ctx_partial_kernel<<<dim3(32, 16), 128, 0, stream>>>(vbf, wout, part);
        ctx_reduce_kernel<<<32, 256, 0, stream>>>(part, out, 16);
    } else {
        // conservative fp32 fallback (no big scratch available)
        float* qpb   = (float*)ws;
        float* spart = (float*)(ws + SZ_QPB);
        float* part  = (float*)(ws + SZ_QPB + (size_t)M_TOT * 4);
        qproj_kernel<<<dim3(32, 4), 256, 0, stream>>>(query, w1, b1, b2, qpb);
        score_fallback_kernel<<<4096, 256, 0, stream>>>(values, w2, qpb, v, spart);
        softmax_kernel<<<32, 256, 0, stream>>>(spart, mask, wout, 1);
        ctx_partial_f32_kernel<<<dim3(32, 8), 256, 0, stream>>>(values, wout, part);
        ctx_reduce_kernel<<<32, 256, 0, stream>>>(part, out, 8);
    }
}